// Round 1
// baseline (855.130 us; speedup 1.0000x reference)
//
#include <hip/hip_runtime.h>
#include <hip/hip_bf16.h>

#define HDIM 512
#define BM 64
#define BN 64
#define BK 16

// ---------------- CSR build ----------------

__global__ void deg_kernel(const int* __restrict__ dst, int* __restrict__ deg, int E) {
    int e = blockIdx.x * blockDim.x + threadIdx.x;
    if (e < E) atomicAdd(&deg[dst[e]], 1);
}

// single-block exclusive scan over N (~10000) elements
__global__ void scan_kernel(const int* __restrict__ deg, int* __restrict__ off, int n) {
    __shared__ int buf[1024];
    __shared__ int base_s;
    int tid = threadIdx.x;
    if (tid == 0) base_s = 0;
    __syncthreads();
    for (int start = 0; start < n; start += 1024) {
        int i = start + tid;
        int v = (i < n) ? deg[i] : 0;
        buf[tid] = v;
        __syncthreads();
        int base = base_s;
        for (int ofs = 1; ofs < 1024; ofs <<= 1) {
            int t = (tid >= ofs) ? buf[tid - ofs] : 0;
            __syncthreads();
            buf[tid] += t;
            __syncthreads();
        }
        if (i < n) off[i] = base + buf[tid] - v;   // exclusive
        int total = buf[1023];
        __syncthreads();
        if (tid == 0) base_s = base + total;
        __syncthreads();
    }
    if (tid == 0) off[n] = base_s;
}

__global__ void fill_csr(const int* __restrict__ src, const int* __restrict__ dst,
                         const int* __restrict__ off, int* __restrict__ cursor,
                         int* __restrict__ csr_src, int E) {
    int e = blockIdx.x * blockDim.x + threadIdx.x;
    if (e < E) {
        int d = dst[e];
        int p = atomicAdd(&cursor[d], 1);
        csr_src[off[d] + p] = src[e];
    }
}

// ---------------- mean aggregation: one wave per destination node ----------------

__global__ __launch_bounds__(256) void aggregate_kernel(
    const float* __restrict__ x, const int* __restrict__ off,
    const int* __restrict__ csr_src, float* __restrict__ agg, int n) {
    int w = (blockIdx.x * 256 + threadIdx.x) >> 6;   // global wave id = node id
    int lane = threadIdx.x & 63;
    if (w >= n) return;
    int beg = off[w], end = off[w + 1];
    float4 a0 = {0.f, 0.f, 0.f, 0.f};
    float4 a1 = {0.f, 0.f, 0.f, 0.f};
    for (int e = beg; e < end; ++e) {
        int s = csr_src[e];
        const float4* p = (const float4*)(x + (size_t)s * HDIM + lane * 8);
        float4 u = p[0];
        float4 v = p[1];
        a0.x += u.x; a0.y += u.y; a0.z += u.z; a0.w += u.w;
        a1.x += v.x; a1.y += v.y; a1.z += v.z; a1.w += v.w;
    }
    float inv = 1.0f / fmaxf((float)(end - beg), 1.0f);
    a0.x *= inv; a0.y *= inv; a0.z *= inv; a0.w *= inv;
    a1.x *= inv; a1.y *= inv; a1.z *= inv; a1.w *= inv;
    float4* o = (float4*)(agg + (size_t)w * HDIM + lane * 8);
    o[0] = a0;
    o[1] = a1;
}

// ---------------- fused dual GEMM: C = act(A1@W1 + A2@W2 + bias) ----------------
// A matrices are [M, 512] row-major (lda = HDIM). W is [K, ldw] row-major.
// K1 and K2 are multiples of BK. K2 == 0 -> single GEMM.

__global__ __launch_bounds__(256) void gemm_dual(
    const float* __restrict__ A1, const float* __restrict__ W1, int K1,
    const float* __restrict__ A2, const float* __restrict__ W2, int K2,
    const float* __restrict__ bias, float* __restrict__ C,
    int M, int ldw, int do_relu) {
    __shared__ float Ast[BK][BM + 4];   // A tile, transposed (k-major)
    __shared__ float Bs[BK][BN + 4];

    int tid = threadIdx.x;
    int row0 = blockIdx.x * BM;
    int col0 = blockIdx.y * BN;
    int tx = tid & 15, ty = tid >> 4;

    int ar = tid >> 2, ac = (tid & 3) * 4;   // A-tile load coords
    int br = tid >> 4, bc = (tid & 15) * 4;  // B-tile load coords

    float acc[4][4] = {};
    int KT = (K1 + K2) / BK;

    for (int kt = 0; kt < KT; ++kt) {
        const float* A;
        const float* W;
        int k0;
        if (kt * BK < K1) { A = A1; W = W1; k0 = kt * BK; }
        else              { A = A2; W = W2; k0 = kt * BK - K1; }

        float4 av = {0.f, 0.f, 0.f, 0.f};
        int grow = row0 + ar;
        if (grow < M) av = *(const float4*)(A + (size_t)grow * HDIM + k0 + ac);
        float4 bv = *(const float4*)(W + (size_t)(k0 + br) * ldw + col0 + bc);

        __syncthreads();   // previous iteration's LDS reads done
        Ast[ac + 0][ar] = av.x;
        Ast[ac + 1][ar] = av.y;
        Ast[ac + 2][ar] = av.z;
        Ast[ac + 3][ar] = av.w;
        *(float4*)&Bs[br][bc] = bv;
        __syncthreads();

#pragma unroll
        for (int kk = 0; kk < BK; ++kk) {
            float4 a = *(const float4*)&Ast[kk][ty * 4];
            float4 b = *(const float4*)&Bs[kk][tx * 4];
            acc[0][0] += a.x * b.x; acc[0][1] += a.x * b.y; acc[0][2] += a.x * b.z; acc[0][3] += a.x * b.w;
            acc[1][0] += a.y * b.x; acc[1][1] += a.y * b.y; acc[1][2] += a.y * b.z; acc[1][3] += a.y * b.w;
            acc[2][0] += a.z * b.x; acc[2][1] += a.z * b.y; acc[2][2] += a.z * b.z; acc[2][3] += a.z * b.w;
            acc[3][0] += a.w * b.x; acc[3][1] += a.w * b.y; acc[3][2] += a.w * b.z; acc[3][3] += a.w * b.w;
        }
    }

    float4 bb = *(const float4*)(bias + col0 + tx * 4);
#pragma unroll
    for (int i = 0; i < 4; ++i) {
        int r = row0 + ty * 4 + i;
        if (r < M) {
            float4 c;
            c.x = acc[i][0] + bb.x;
            c.y = acc[i][1] + bb.y;
            c.z = acc[i][2] + bb.z;
            c.w = acc[i][3] + bb.w;
            if (do_relu) {
                c.x = fmaxf(c.x, 0.f); c.y = fmaxf(c.y, 0.f);
                c.z = fmaxf(c.z, 0.f); c.w = fmaxf(c.w, 0.f);
            }
            *(float4*)(C + (size_t)r * ldw + col0 + tx * 4) = c;
        }
    }
}

// ---------------- launch ----------------

extern "C" void kernel_launch(void* const* d_in, const int* in_sizes, int n_in,
                              void* d_out, int out_size, void* d_ws, size_t ws_size,
                              hipStream_t stream) {
    const float* x    = (const float*)d_in[0];
    const int*   ei   = (const int*)d_in[1];
    const float* wl0  = (const float*)d_in[2];
    const float* bl0  = (const float*)d_in[3];
    const float* wr0  = (const float*)d_in[4];
    const float* wl1  = (const float*)d_in[5];
    const float* bl1  = (const float*)d_in[6];
    const float* wr1  = (const float*)d_in[7];
    const float* wl2  = (const float*)d_in[8];
    const float* bl2  = (const float*)d_in[9];
    const float* wr2  = (const float*)d_in[10];
    const float* wout = (const float*)d_in[11];
    const float* bout = (const float*)d_in[12];

    int N = in_sizes[0] / HDIM;   // 10000
    int E = in_sizes[1] / 2;      // 160000
    int O = in_sizes[12];         // 128

    const int* src = ei;
    const int* dst = ei + E;

    char* ws = (char*)d_ws;
    auto align = [](size_t o) { return (o + 255) & ~(size_t)255; };
    size_t o = 0;
    int* deg     = (int*)(ws + o); o = align(o + (size_t)N * 4);
    int* cursor  = (int*)(ws + o); o = align(o + (size_t)N * 4);
    int* off     = (int*)(ws + o); o = align(o + (size_t)(N + 1) * 4);
    int* csr_src = (int*)(ws + o); o = align(o + (size_t)E * 4);
    float* agg   = (float*)(ws + o); o = align(o + (size_t)N * HDIM * 4);
    float* hA    = (float*)(ws + o); o = align(o + (size_t)N * HDIM * 4);
    float* hB    = (float*)(ws + o); o = align(o + (size_t)N * HDIM * 4);

    hipMemsetAsync(deg, 0, (size_t)N * 4, stream);
    hipMemsetAsync(cursor, 0, (size_t)N * 4, stream);

    deg_kernel<<<(E + 255) / 256, 256, 0, stream>>>(dst, deg, E);
    scan_kernel<<<1, 1024, 0, stream>>>(deg, off, N);
    fill_csr<<<(E + 255) / 256, 256, 0, stream>>>(src, dst, off, cursor, csr_src, E);

    dim3 gl((N + BM - 1) / BM, HDIM / BN);
    dim3 go((N + BM - 1) / BM, O / BN);
    int aggBlocks = (N + 3) / 4;

    // layer 0
    aggregate_kernel<<<aggBlocks, 256, 0, stream>>>(x, off, csr_src, agg, N);
    gemm_dual<<<gl, 256, 0, stream>>>(agg, wl0, HDIM, x, wr0, HDIM, bl0, hA, N, HDIM, 1);
    // layer 1
    aggregate_kernel<<<aggBlocks, 256, 0, stream>>>(hA, off, csr_src, agg, N);
    gemm_dual<<<gl, 256, 0, stream>>>(agg, wl1, HDIM, hA, wr1, HDIM, bl1, hB, N, HDIM, 1);
    // layer 2
    aggregate_kernel<<<aggBlocks, 256, 0, stream>>>(hB, off, csr_src, agg, N);
    gemm_dual<<<gl, 256, 0, stream>>>(agg, wl2, HDIM, hB, wr2, HDIM, bl2, hA, N, HDIM, 1);
    // output projection
    gemm_dual<<<go, 256, 0, stream>>>(hA, wout, HDIM, nullptr, nullptr, 0, bout,
                                      (float*)d_out, N, O, 0);
}

// Round 2
// 572.538 us; speedup vs baseline: 1.4936x; 1.4936x over previous
//
#include <hip/hip_runtime.h>
#include <hip/hip_bf16.h>

#define NNODES_DIM 512

typedef short s16x8 __attribute__((ext_vector_type(8)));
typedef float f32x4 __attribute__((ext_vector_type(4)));
typedef unsigned short u16x8 __attribute__((ext_vector_type(8)));

static __device__ __forceinline__ float bf2f(unsigned short b) {
    union { unsigned int u; float f; } cv;
    cv.u = ((unsigned int)b) << 16;
    return cv.f;
}
static __device__ __forceinline__ unsigned short f2bf(float v) {
    __hip_bfloat16 h = __float2bfloat16(v);
    return *reinterpret_cast<unsigned short*>(&h);
}

// ---------------- CSR build ----------------

__global__ void deg_kernel(const int* __restrict__ dst, int* __restrict__ deg, int E) {
    int e = blockIdx.x * blockDim.x + threadIdx.x;
    if (e < E) atomicAdd(&deg[dst[e]], 1);
}

__global__ void scan_kernel(const int* __restrict__ deg, int* __restrict__ off, int n) {
    __shared__ int buf[1024];
    __shared__ int base_s;
    int tid = threadIdx.x;
    if (tid == 0) base_s = 0;
    __syncthreads();
    for (int start = 0; start < n; start += 1024) {
        int i = start + tid;
        int v = (i < n) ? deg[i] : 0;
        buf[tid] = v;
        __syncthreads();
        int base = base_s;
        for (int ofs = 1; ofs < 1024; ofs <<= 1) {
            int t = (tid >= ofs) ? buf[tid - ofs] : 0;
            __syncthreads();
            buf[tid] += t;
            __syncthreads();
        }
        if (i < n) off[i] = base + buf[tid] - v;
        int total = buf[1023];
        __syncthreads();
        if (tid == 0) base_s = base + total;
        __syncthreads();
    }
    if (tid == 0) off[n] = base_s;
}

__global__ void fill_csr(const int* __restrict__ src, const int* __restrict__ dst,
                         const int* __restrict__ off, int* __restrict__ cursor,
                         int* __restrict__ csr_src, int E) {
    int e = blockIdx.x * blockDim.x + threadIdx.x;
    if (e < E) {
        int d = dst[e];
        int p = atomicAdd(&cursor[d], 1);
        csr_src[off[d] + p] = src[e];
    }
}

// ---------------- conversions ----------------

// x fp32 [M*512] -> hi/lo bf16 planes
__global__ void conv_x_kernel(const float* __restrict__ x,
                              unsigned short* __restrict__ hi,
                              unsigned short* __restrict__ lo, int total4) {
    int i = blockIdx.x * blockDim.x + threadIdx.x;
    if (i >= total4) return;
    float4 v = *(const float4*)(x + (size_t)i * 4);
    ushort4 h, l;
    h.x = f2bf(v.x); l.x = f2bf(v.x - bf2f(h.x));
    h.y = f2bf(v.y); l.y = f2bf(v.y - bf2f(h.y));
    h.z = f2bf(v.z); l.z = f2bf(v.z - bf2f(h.z));
    h.w = f2bf(v.w); l.w = f2bf(v.w - bf2f(h.w));
    *(ushort4*)(hi + (size_t)i * 4) = h;
    *(ushort4*)(lo + (size_t)i * 4) = l;
}

// W [K][Nw] fp32 -> W^T hi/lo bf16 [Nw][K]
__global__ void conv_w_kernel(const float* __restrict__ W,
                              unsigned short* __restrict__ Thi,
                              unsigned short* __restrict__ Tlo, int K, int Nw) {
    __shared__ float t[32][33];
    int tx = threadIdx.x & 31, ty = threadIdx.x >> 5;
    int k0 = blockIdx.x * 32, n0 = blockIdx.y * 32;
#pragma unroll
    for (int j = 0; j < 4; ++j) {
        int r = ty + j * 8;
        t[r][tx] = W[(size_t)(k0 + r) * Nw + n0 + tx];
    }
    __syncthreads();
#pragma unroll
    for (int j = 0; j < 4; ++j) {
        int rn = ty + j * 8;
        float v = t[tx][rn];
        unsigned short h = f2bf(v);
        unsigned short l = f2bf(v - bf2f(h));
        size_t idx = (size_t)(n0 + rn) * K + k0 + tx;
        Thi[idx] = h;
        Tlo[idx] = l;
    }
}

// ---------------- mean aggregation on bf16 planes: one wave per node ----------------

__global__ __launch_bounds__(256) void aggregate_planes(
    const unsigned short* __restrict__ hi, const unsigned short* __restrict__ lo,
    const int* __restrict__ off, const int* __restrict__ csr_src,
    unsigned short* __restrict__ ahi, unsigned short* __restrict__ alo, int n) {
    int w = (blockIdx.x * 256 + threadIdx.x) >> 6;
    int lane = threadIdx.x & 63;
    if (w >= n) return;
    int beg = off[w], end = off[w + 1];
    int c0 = lane * 8;
    float a[8] = {0.f, 0.f, 0.f, 0.f, 0.f, 0.f, 0.f, 0.f};
    for (int e = beg; e < end; ++e) {
        int s = csr_src[e];
        u16x8 vh = *(const u16x8*)(hi + (size_t)s * NNODES_DIM + c0);
        u16x8 vl = *(const u16x8*)(lo + (size_t)s * NNODES_DIM + c0);
#pragma unroll
        for (int j = 0; j < 8; ++j) a[j] += bf2f(vh[j]) + bf2f(vl[j]);
    }
    float inv = 1.0f / fmaxf((float)(end - beg), 1.0f);
    u16x8 oh, ol;
#pragma unroll
    for (int j = 0; j < 8; ++j) {
        float v = a[j] * inv;
        unsigned short h = f2bf(v);
        oh[j] = h;
        ol[j] = f2bf(v - bf2f(h));
    }
    *(u16x8*)(ahi + (size_t)w * NNODES_DIM + c0) = oh;
    *(u16x8*)(alo + (size_t)w * NNODES_DIM + c0) = ol;
}

// ---------------- MFMA GEMM over K-segments ----------------
// Each segment s: A-plane [M][512] bf16, B-plane (W^T) [N][512] bf16.
// C = sum_s A_s @ B_s^T  (+bias, relu). Output either fp32 (outF) or hi/lo planes.

struct Segs {
    const unsigned short* a[6];
    const unsigned short* b[6];
};

template<int BM, int BN>
__global__ __launch_bounds__(256) void gemm_mfma(
    Segs segs, int nseg, const float* __restrict__ bias,
    float* __restrict__ outF, unsigned short* __restrict__ outHi,
    unsigned short* __restrict__ outLo, int M, int ldo, int relu) {
    constexpr int FM = BM / 32;    // 16-row frags per wave (wave tile BM/2)
    constexpr int FN = BN / 32;
    __shared__ unsigned short As[BM * 64];
    __shared__ unsigned short Bs[BN * 64];

    int tid = threadIdx.x;
    int lane = tid & 63;
    int wid = tid >> 6;
    int rowBase = blockIdx.x * BM;
    int colBase = blockIdx.y * BN;
    int wm = (wid >> 1) * (BM / 2);
    int wn = (wid & 1) * (BN / 2);

    f32x4 acc[FM][FN] = {};

    int srow = lane >> 3;          // 0..7
    int scol = (lane & 7) * 8;     // element col within 64
    int nsteps = nseg * 8;         // 8 K-steps of 64 per 512-segment

    for (int kt = 0; kt < nsteps; ++kt) {
        int seg = kt >> 3;
        int k0 = (kt & 7) * 64;
        const unsigned short* pa = segs.a[seg];
        const unsigned short* pb = segs.b[seg];

#pragma unroll
        for (int s = 0; s < BM / 32; ++s) {
            int r = wid * (BM / 4) + s * 8;
            int gr = rowBase + r + srow;
            if (gr >= M) gr = M - 1;
            const unsigned short* g = pa + (size_t)gr * NNODES_DIM + k0 + scol;
            __builtin_amdgcn_global_load_lds(
                (const __attribute__((address_space(1))) unsigned int*)g,
                (__attribute__((address_space(3))) unsigned int*)&As[r * 64],
                16, 0, 0);
        }
#pragma unroll
        for (int s = 0; s < BN / 32; ++s) {
            int r = wid * (BN / 4) + s * 8;
            const unsigned short* g = pb + (size_t)(colBase + r + srow) * NNODES_DIM + k0 + scol;
            __builtin_amdgcn_global_load_lds(
                (const __attribute__((address_space(1))) unsigned int*)g,
                (__attribute__((address_space(3))) unsigned int*)&Bs[r * 64],
                16, 0, 0);
        }
        __syncthreads();

#pragma unroll
        for (int kk = 0; kk < 2; ++kk) {
            s16x8 aF[FM], bF[FN];
#pragma unroll
            for (int m = 0; m < FM; ++m)
                aF[m] = *(const s16x8*)&As[(wm + m * 16 + (lane & 15)) * 64 + kk * 32 + (lane >> 4) * 8];
#pragma unroll
            for (int n = 0; n < FN; ++n)
                bF[n] = *(const s16x8*)&Bs[(wn + n * 16 + (lane & 15)) * 64 + kk * 32 + (lane >> 4) * 8];
#pragma unroll
            for (int m = 0; m < FM; ++m)
#pragma unroll
                for (int n = 0; n < FN; ++n)
                    acc[m][n] = __builtin_amdgcn_mfma_f32_16x16x32_bf16(aF[m], bF[n], acc[m][n], 0, 0, 0);
        }
        __syncthreads();
    }

#pragma unroll
    for (int n = 0; n < FN; ++n) {
        int col = colBase + wn + n * 16 + (lane & 15);
        float bb = bias[col];
#pragma unroll
        for (int m = 0; m < FM; ++m) {
            int row0 = rowBase + wm + m * 16 + (lane >> 4) * 4;
#pragma unroll
            for (int r = 0; r < 4; ++r) {
                int row = row0 + r;
                if (row < M) {
                    float v = acc[m][n][r] + bb;
                    if (relu) v = fmaxf(v, 0.f);
                    if (outF) {
                        outF[(size_t)row * ldo + col] = v;
                    } else {
                        unsigned short h = f2bf(v);
                        outHi[(size_t)row * NNODES_DIM + col] = h;
                        outLo[(size_t)row * NNODES_DIM + col] = f2bf(v - bf2f(h));
                    }
                }
            }
        }
    }
}

// ---------------- launch ----------------

extern "C" void kernel_launch(void* const* d_in, const int* in_sizes, int n_in,
                              void* d_out, int out_size, void* d_ws, size_t ws_size,
                              hipStream_t stream) {
    const float* x    = (const float*)d_in[0];
    const int*   ei   = (const int*)d_in[1];
    const float* wl0  = (const float*)d_in[2];
    const float* bl0  = (const float*)d_in[3];
    const float* wr0  = (const float*)d_in[4];
    const float* wl1  = (const float*)d_in[5];
    const float* bl1  = (const float*)d_in[6];
    const float* wr1  = (const float*)d_in[7];
    const float* wl2  = (const float*)d_in[8];
    const float* bl2  = (const float*)d_in[9];
    const float* wr2  = (const float*)d_in[10];
    const float* wout = (const float*)d_in[11];
    const float* bout = (const float*)d_in[12];

    int N = in_sizes[0] / NNODES_DIM;   // 10000
    int E = in_sizes[1] / 2;            // 160000
    int O = in_sizes[12];               // 128

    const int* src = ei;
    const int* dst = ei + E;

    char* ws = (char*)d_ws;
    auto align = [](size_t o) { return (o + 255) & ~(size_t)255; };
    size_t o = 0;
    int* deg     = (int*)(ws + o); o = align(o + (size_t)N * 4);
    int* cursor  = (int*)(ws + o); o = align(o + (size_t)N * 4);
    int* off     = (int*)(ws + o); o = align(o + (size_t)(N + 1) * 4);
    int* csr_src = (int*)(ws + o); o = align(o + (size_t)E * 4);

    size_t planeB = (size_t)N * NNODES_DIM * 2;   // bf16 plane bytes
    unsigned short* x_hi  = (unsigned short*)(ws + o); o = align(o + planeB);
    unsigned short* x_lo  = (unsigned short*)(ws + o); o = align(o + planeB);
    unsigned short* ag_hi = (unsigned short*)(ws + o); o = align(o + planeB);
    unsigned short* ag_lo = (unsigned short*)(ws + o); o = align(o + planeB);
    unsigned short* hA_hi = (unsigned short*)(ws + o); o = align(o + planeB);
    unsigned short* hA_lo = (unsigned short*)(ws + o); o = align(o + planeB);
    unsigned short* hB_hi = (unsigned short*)(ws + o); o = align(o + planeB);
    unsigned short* hB_lo = (unsigned short*)(ws + o); o = align(o + planeB);

    size_t wB = (size_t)512 * 512 * 2;   // transposed weight plane (bf16)
    unsigned short* wT[14];              // {wl0,wr0,wl1,wr1,wl2,wr2} hi/lo + wout hi/lo
    for (int i = 0; i < 12; ++i) { wT[i] = (unsigned short*)(ws + o); o = align(o + wB); }
    size_t woB = (size_t)O * 512 * 2;
    wT[12] = (unsigned short*)(ws + o); o = align(o + woB);
    wT[13] = (unsigned short*)(ws + o); o = align(o + woB);

    hipMemsetAsync(deg, 0, (size_t)N * 4, stream);
    hipMemsetAsync(cursor, 0, (size_t)N * 4, stream);

    deg_kernel<<<(E + 255) / 256, 256, 0, stream>>>(dst, deg, E);
    scan_kernel<<<1, 1024, 0, stream>>>(deg, off, N);
    fill_csr<<<(E + 255) / 256, 256, 0, stream>>>(src, dst, off, cursor, csr_src, E);

    conv_x_kernel<<<(N * NNODES_DIM / 4 + 255) / 256, 256, 0, stream>>>(x, x_hi, x_lo, N * NNODES_DIM / 4);
    dim3 wgrid(16, 16);
    conv_w_kernel<<<wgrid, 256, 0, stream>>>(wl0, wT[0], wT[1], 512, 512);
    conv_w_kernel<<<wgrid, 256, 0, stream>>>(wr0, wT[2], wT[3], 512, 512);
    conv_w_kernel<<<wgrid, 256, 0, stream>>>(wl1, wT[4], wT[5], 512, 512);
    conv_w_kernel<<<wgrid, 256, 0, stream>>>(wr1, wT[6], wT[7], 512, 512);
    conv_w_kernel<<<wgrid, 256, 0, stream>>>(wl2, wT[8], wT[9], 512, 512);
    conv_w_kernel<<<wgrid, 256, 0, stream>>>(wr2, wT[10], wT[11], 512, 512);
    dim3 wogrid(16, O / 32);
    conv_w_kernel<<<wogrid, 256, 0, stream>>>(wout, wT[12], wT[13], 512, O);

    int aggBlocks = (N + 3) / 4;
    dim3 ghid((N + 127) / 128, 4);       // 128x128 tiles, N=512 cols
    dim3 gout((N + 63) / 64, O / 64);    // 64x64 tiles, O=128 cols

    // layer 0
    aggregate_planes<<<aggBlocks, 256, 0, stream>>>(x_hi, x_lo, off, csr_src, ag_hi, ag_lo, N);
    {
        Segs s = {{ag_hi, x_hi, ag_lo, x_lo, ag_hi, x_hi},
                  {wT[0], wT[2], wT[0], wT[2], wT[1], wT[3]}};
        gemm_mfma<128, 128><<<ghid, 256, 0, stream>>>(s, 6, bl0, nullptr, hA_hi, hA_lo, N, 512, 1);
    }
    // layer 1
    aggregate_planes<<<aggBlocks, 256, 0, stream>>>(hA_hi, hA_lo, off, csr_src, ag_hi, ag_lo, N);
    {
        Segs s = {{ag_hi, hA_hi, ag_lo, hA_lo, ag_hi, hA_hi},
                  {wT[4], wT[6], wT[4], wT[6], wT[5], wT[7]}};
        gemm_mfma<128, 128><<<ghid, 256, 0, stream>>>(s, 6, bl1, nullptr, hB_hi, hB_lo, N, 512, 1);
    }
    // layer 2 (reuse hA planes for output activations)
    aggregate_planes<<<aggBlocks, 256, 0, stream>>>(hB_hi, hB_lo, off, csr_src, ag_hi, ag_lo, N);
    {
        Segs s = {{ag_hi, hB_hi, ag_lo, hB_lo, ag_hi, hB_hi},
                  {wT[8], wT[10], wT[8], wT[10], wT[9], wT[11]}};
        gemm_mfma<128, 128><<<ghid, 256, 0, stream>>>(s, 6, bl2, nullptr, hA_hi, hA_lo, N, 512, 1);
    }
    // output projection
    {
        Segs s = {{hA_hi, hA_lo, hA_hi, nullptr, nullptr, nullptr},
                  {wT[12], wT[12], wT[13], nullptr, nullptr, nullptr}};
        gemm_mfma<64, 64><<<gout, 256, 0, stream>>>(s, 3, bout, (float*)d_out, nullptr, nullptr, N, O, 0);
    }
}

// Round 3
// 463.872 us; speedup vs baseline: 1.8435x; 1.2343x over previous
//
#include <hip/hip_runtime.h>
#include <hip/hip_bf16.h>

#define KDIM 512

typedef short s16x8 __attribute__((ext_vector_type(8)));
typedef float f32x4 __attribute__((ext_vector_type(4)));
typedef unsigned short u16x8 __attribute__((ext_vector_type(8)));

static __device__ __forceinline__ float bf2f(unsigned short b) {
    union { unsigned int u; float f; } cv;
    cv.u = ((unsigned int)b) << 16;
    return cv.f;
}
static __device__ __forceinline__ unsigned short f2bf(float v) {
    __hip_bfloat16 h = __float2bfloat16(v);
    return *reinterpret_cast<unsigned short*>(&h);
}

// ---------------- CSR build ----------------

__global__ void deg_kernel(const int* __restrict__ dst, int* __restrict__ deg, int E) {
    int e = blockIdx.x * blockDim.x + threadIdx.x;
    if (e < E) atomicAdd(&deg[dst[e]], 1);
}

// single-block scan, wave-shuffle based (2 barriers per 1024-chunk)
__global__ void scan_kernel(const int* __restrict__ deg, int* __restrict__ off, int n) {
    __shared__ int wsum[16];
    __shared__ int carry;
    int tid = threadIdx.x;
    int lane = tid & 63, wv = tid >> 6;
    if (tid == 0) carry = 0;
    __syncthreads();
    for (int start = 0; start < n; start += 1024) {
        int i = start + tid;
        int orig = (i < n) ? deg[i] : 0;
        int v = orig;
#pragma unroll
        for (int d = 1; d < 64; d <<= 1) {
            int t = __shfl_up(v, d, 64);
            if (lane >= d) v += t;
        }
        if (lane == 63) wsum[wv] = v;
        __syncthreads();
        int base = carry;
        if (wv == 0 && lane < 16) {
            int s = wsum[lane];
#pragma unroll
            for (int d = 1; d < 16; d <<= 1) {
                int t = __shfl_up(s, d, 64);
                if (lane >= d) s += t;
            }
            wsum[lane] = s;
            if (lane == 15) carry = base + s;
        }
        __syncthreads();
        int wpre = (wv == 0) ? 0 : wsum[wv - 1];
        if (i < n) off[i] = base + wpre + v - orig;   // exclusive
        __syncthreads();
    }
    if (tid == 0) off[n] = carry;
}

__global__ void fill_csr(const int* __restrict__ src, const int* __restrict__ dst,
                         const int* __restrict__ off, int* __restrict__ cursor,
                         int* __restrict__ csr_src, int E) {
    int e = blockIdx.x * blockDim.x + threadIdx.x;
    if (e < E) {
        int d = dst[e];
        int p = atomicAdd(&cursor[d], 1);
        csr_src[off[d] + p] = src[e];
    }
}

// ---------------- conversions ----------------

__global__ void conv_x_kernel(const float* __restrict__ x,
                              unsigned short* __restrict__ hi,
                              unsigned short* __restrict__ lo, int total4) {
    int i = blockIdx.x * blockDim.x + threadIdx.x;
    if (i >= total4) return;
    float4 v = *(const float4*)(x + (size_t)i * 4);
    ushort4 h, l;
    h.x = f2bf(v.x); l.x = f2bf(v.x - bf2f(h.x));
    h.y = f2bf(v.y); l.y = f2bf(v.y - bf2f(h.y));
    h.z = f2bf(v.z); l.z = f2bf(v.z - bf2f(h.z));
    h.w = f2bf(v.w); l.w = f2bf(v.w - bf2f(h.w));
    *(ushort4*)(hi + (size_t)i * 4) = h;
    *(ushort4*)(lo + (size_t)i * 4) = l;
}

// W [K][Nw] fp32 -> W^T hi/lo bf16 [Nw][K], K = 512 (output row stride 512)
__global__ void conv_w_kernel(const float* __restrict__ W,
                              unsigned short* __restrict__ Thi,
                              unsigned short* __restrict__ Tlo, int Nw) {
    __shared__ float t[32][33];
    int tx = threadIdx.x & 31, ty = threadIdx.x >> 5;
    int k0 = blockIdx.x * 32, n0 = blockIdx.y * 32;
#pragma unroll
    for (int j = 0; j < 4; ++j) {
        int r = ty + j * 8;
        t[r][tx] = W[(size_t)(k0 + r) * Nw + n0 + tx];
    }
    __syncthreads();
#pragma unroll
    for (int j = 0; j < 4; ++j) {
        int rn = ty + j * 8;
        float v = t[tx][rn];
        unsigned short h = f2bf(v);
        unsigned short l = f2bf(v - bf2f(h));
        size_t idx = (size_t)(n0 + rn) * KDIM + k0 + tx;
        Thi[idx] = h;
        Tlo[idx] = l;
    }
}

// ---------------- MFMA GEMM over K-segments ----------------
// A-plane [M][512] bf16, B-plane (W^T) [Nw][512] bf16. C = sum_s A_s @ B_s^T.
// LDS tiles XOR-swizzled (chunk ^ (row&7)) via pre-swizzled global source.
// 1D grid with bijective XCD chunking: consecutive tiles (same row-block,
// different col-block) land on the same XCD -> A panel L2-reuse.

struct Segs {
    const unsigned short* a[3];
    const unsigned short* b[3];
};

template<int BM, int BN>
__global__ __launch_bounds__(256) void gemm_mfma(
    Segs segs, int nseg, const float* __restrict__ bias,
    float* __restrict__ out, int M, int ldo, int NBY, int relu) {
    constexpr int FM = BM / 32;
    constexpr int FN = BN / 32;
    __shared__ unsigned short As[BM * 64];
    __shared__ unsigned short Bs[BN * 64];

    int tid = threadIdx.x;
    int lane = tid & 63;
    int wid = tid >> 6;

    // bijective XCD chunk map (m204)
    int nwg = gridDim.x;
    int q = nwg >> 3, rres = nwg & 7;
    int xcd = blockIdx.x & 7;
    int tile = (xcd < rres ? xcd * (q + 1) : rres * (q + 1) + (xcd - rres) * q)
             + (blockIdx.x >> 3);
    int rowBase = (tile / NBY) * BM;
    int colBase = (tile % NBY) * BN;

    int wm = (wid >> 1) * (BM / 2);
    int wn = (wid & 1) * (BN / 2);

    f32x4 acc[FM][FN] = {};

    int srow = lane >> 3;                       // 0..7
    int scol = ((lane & 7) ^ srow) * 8;         // pre-swizzled source chunk

    int nsteps = nseg * 8;
    for (int kt = 0; kt < nsteps; ++kt) {
        int seg = kt >> 3;
        int k0 = (kt & 7) * 64;
        const unsigned short* pa = segs.a[seg];
        const unsigned short* pb = segs.b[seg];

#pragma unroll
        for (int s = 0; s < BM / 32; ++s) {
            int r0 = wid * (BM / 4) + s * 8;
            int gr = rowBase + r0 + srow;
            if (gr >= M) gr = M - 1;
            const unsigned short* g = pa + (size_t)gr * KDIM + k0 + scol;
            __builtin_amdgcn_global_load_lds(
                (const __attribute__((address_space(1))) unsigned int*)g,
                (__attribute__((address_space(3))) unsigned int*)&As[r0 * 64],
                16, 0, 0);
        }
#pragma unroll
        for (int s = 0; s < BN / 32; ++s) {
            int r0 = wid * (BN / 4) + s * 8;
            const unsigned short* g = pb + (size_t)(colBase + r0 + srow) * KDIM + k0 + scol;
            __builtin_amdgcn_global_load_lds(
                (const __attribute__((address_space(1))) unsigned int*)g,
                (__attribute__((address_space(3))) unsigned int*)&Bs[r0 * 64],
                16, 0, 0);
        }
        __syncthreads();

#pragma unroll
        for (int kk = 0; kk < 2; ++kk) {
            s16x8 aF[FM], bF[FN];
#pragma unroll
            for (int m = 0; m < FM; ++m) {
                int rr = wm + m * 16 + (lane & 15);
                int slot = ((kk << 2) + (lane >> 4)) ^ (lane & 7);
                aF[m] = *(const s16x8*)&As[rr * 64 + slot * 8];
            }
#pragma unroll
            for (int n = 0; n < FN; ++n) {
                int rn = wn + n * 16 + (lane & 15);
                int slot = ((kk << 2) + (lane >> 4)) ^ (lane & 7);
                bF[n] = *(const s16x8*)&Bs[rn * 64 + slot * 8];
            }
#pragma unroll
            for (int m = 0; m < FM; ++m)
#pragma unroll
                for (int n = 0; n < FN; ++n)
                    acc[m][n] = __builtin_amdgcn_mfma_f32_16x16x32_bf16(aF[m], bF[n], acc[m][n], 0, 0, 0);
        }
        __syncthreads();
    }

#pragma unroll
    for (int n = 0; n < FN; ++n) {
        int col = colBase + wn + n * 16 + (lane & 15);
        float bb = bias ? bias[col] : 0.0f;
#pragma unroll
        for (int m = 0; m < FM; ++m) {
            int row0 = rowBase + wm + m * 16 + (lane >> 4) * 4;
#pragma unroll
            for (int r = 0; r < 4; ++r) {
                int row = row0 + r;
                if (row < M) {
                    float v = acc[m][n][r] + bb;
                    if (relu) v = fmaxf(v, 0.f);
                    out[(size_t)row * ldo + col] = v;
                }
            }
        }
    }
}

// ---------------- fused gather epilogue ----------------
// next = relu(mean_gather(P[:, :512]) + P[:, 512:] + b), split into hi/lo planes.

__global__ __launch_bounds__(256) void gather_epi(
    const float* __restrict__ P, const int* __restrict__ off,
    const int* __restrict__ csr_src, const float* __restrict__ bias,
    unsigned short* __restrict__ ohi, unsigned short* __restrict__ olo, int n) {
    int w = (blockIdx.x * 256 + threadIdx.x) >> 6;
    int lane = threadIdx.x & 63;
    if (w >= n) return;
    int beg = off[w], end = off[w + 1];
    int c0 = lane * 8;
    float a[8] = {0.f, 0.f, 0.f, 0.f, 0.f, 0.f, 0.f, 0.f};
    for (int e = beg; e < end; ++e) {
        int s = csr_src[e];
        const float4* p = (const float4*)(P + (size_t)s * 1024 + c0);
        float4 u = p[0], v = p[1];
        a[0] += u.x; a[1] += u.y; a[2] += u.z; a[3] += u.w;
        a[4] += v.x; a[5] += v.y; a[6] += v.z; a[7] += v.w;
    }
    float inv = 1.0f / fmaxf((float)(end - beg), 1.0f);
    const float4* p2 = (const float4*)(P + (size_t)w * 1024 + 512 + c0);
    float4 u2 = p2[0], v2 = p2[1];
    const float4* pb = (const float4*)(bias + c0);
    float4 b0 = pb[0], b1 = pb[1];
    float vals[8];
    vals[0] = a[0] * inv + u2.x + b0.x;
    vals[1] = a[1] * inv + u2.y + b0.y;
    vals[2] = a[2] * inv + u2.z + b0.z;
    vals[3] = a[3] * inv + u2.w + b0.w;
    vals[4] = a[4] * inv + v2.x + b1.x;
    vals[5] = a[5] * inv + v2.y + b1.y;
    vals[6] = a[6] * inv + v2.z + b1.z;
    vals[7] = a[7] * inv + v2.w + b1.w;
    u16x8 oh, ol;
#pragma unroll
    for (int j = 0; j < 8; ++j) {
        float v = fmaxf(vals[j], 0.f);
        unsigned short h = f2bf(v);
        oh[j] = h;
        ol[j] = f2bf(v - bf2f(h));
    }
    *(u16x8*)(ohi + (size_t)w * KDIM + c0) = oh;
    *(u16x8*)(olo + (size_t)w * KDIM + c0) = ol;
}

// ---------------- launch ----------------

extern "C" void kernel_launch(void* const* d_in, const int* in_sizes, int n_in,
                              void* d_out, int out_size, void* d_ws, size_t ws_size,
                              hipStream_t stream) {
    const float* x    = (const float*)d_in[0];
    const int*   ei   = (const int*)d_in[1];
    const float* wl0  = (const float*)d_in[2];
    const float* bl0  = (const float*)d_in[3];
    const float* wr0  = (const float*)d_in[4];
    const float* wl1  = (const float*)d_in[5];
    const float* bl1  = (const float*)d_in[6];
    const float* wr1  = (const float*)d_in[7];
    const float* wl2  = (const float*)d_in[8];
    const float* bl2  = (const float*)d_in[9];
    const float* wr2  = (const float*)d_in[10];
    const float* wout = (const float*)d_in[11];
    const float* bout = (const float*)d_in[12];

    int N = in_sizes[0] / KDIM;     // 10000 nodes
    int E = in_sizes[1] / 2;        // 160000 edges
    int O = in_sizes[12];           // 128

    const int* src = ei;
    const int* dst = ei + E;

    char* ws = (char*)d_ws;
    auto align = [](size_t o) { return (o + 255) & ~(size_t)255; };
    size_t o = 0;
    int* deg     = (int*)(ws + o); o = align(o + (size_t)N * 4);
    int* cursor  = (int*)(ws + o); o = align(o + (size_t)N * 4);
    int* off     = (int*)(ws + o); o = align(o + (size_t)(N + 1) * 4);
    int* csr_src = (int*)(ws + o); o = align(o + (size_t)E * 4);

    size_t planeB = (size_t)N * KDIM * 2;
    unsigned short* x_hi = (unsigned short*)(ws + o); o = align(o + planeB);
    unsigned short* x_lo = (unsigned short*)(ws + o); o = align(o + planeB);
    unsigned short* a_hi = (unsigned short*)(ws + o); o = align(o + planeB);
    unsigned short* a_lo = (unsigned short*)(ws + o); o = align(o + planeB);
    float* P = (float*)(ws + o); o = align(o + (size_t)N * 1024 * 4);

    // W^T planes: 3 hidden layers, each [1024][512] hi+lo; output [128][512] hi+lo
    size_t whB = (size_t)1024 * KDIM * 2;
    unsigned short* WThi[3];
    unsigned short* WTlo[3];
    for (int i = 0; i < 3; ++i) {
        WThi[i] = (unsigned short*)(ws + o); o = align(o + whB);
        WTlo[i] = (unsigned short*)(ws + o); o = align(o + whB);
    }
    size_t woB = (size_t)O * KDIM * 2;
    unsigned short* WoThi = (unsigned short*)(ws + o); o = align(o + woB);
    unsigned short* WoTlo = (unsigned short*)(ws + o); o = align(o + woB);

    hipMemsetAsync(deg, 0, (size_t)N * 4, stream);
    hipMemsetAsync(cursor, 0, (size_t)N * 4, stream);

    deg_kernel<<<(E + 255) / 256, 256, 0, stream>>>(dst, deg, E);
    scan_kernel<<<1, 1024, 0, stream>>>(deg, off, N);
    fill_csr<<<(E + 255) / 256, 256, 0, stream>>>(src, dst, off, cursor, csr_src, E);

    conv_x_kernel<<<(N * KDIM / 4 + 255) / 256, 256, 0, stream>>>(x, x_hi, x_lo, N * KDIM / 4);

    dim3 wgrid(16, 16);
    const float* wl[3] = {wl0, wl1, wl2};
    const float* wr[3] = {wr0, wr1, wr2};
    for (int i = 0; i < 3; ++i) {
        conv_w_kernel<<<wgrid, 256, 0, stream>>>(wl[i], WThi[i], WTlo[i], 512);
        conv_w_kernel<<<wgrid, 256, 0, stream>>>(wr[i], WThi[i] + (size_t)512 * KDIM,
                                                 WTlo[i] + (size_t)512 * KDIM, 512);
    }
    dim3 wogrid(16, O / 32);
    conv_w_kernel<<<wogrid, 256, 0, stream>>>(wout, WoThi, WoTlo, O);

    int nbx = (N + 127) / 128;            // 79
    int nwgH = nbx * 8;                   // 632 (N_out = 1024, BN = 128)
    int aggBlocks = (N + 3) / 4;
    const float* bl[3] = {bl0, bl1, bl2};

    // ping-pong plane buffers: X0 = x planes, X1 = a planes, X2 = x planes, X3 = a planes
    unsigned short* inHi[4]  = {x_hi, a_hi, x_hi, a_hi};
    unsigned short* inLo[4]  = {x_lo, a_lo, x_lo, a_lo};

    for (int i = 0; i < 3; ++i) {
        Segs s = {{inHi[i], inLo[i], inHi[i]}, {WThi[i], WThi[i], WTlo[i]}};
        gemm_mfma<128, 128><<<nwgH, 256, 0, stream>>>(s, 3, nullptr, P, N, 1024, 8, 0);
        gather_epi<<<aggBlocks, 256, 0, stream>>>(P, off, csr_src, bl[i], inHi[i + 1], inLo[i + 1], N);
    }

    // output projection: [N,512] @ [512,128] + bout
    {
        Segs s = {{inHi[3], inLo[3], inHi[3]}, {WoThi, WoThi, WoTlo}};
        int nwgO = ((N + 63) / 64) * (O / 64);   // 157 * 2 = 314
        gemm_mfma<64, 64><<<nwgO, 256, 0, stream>>>(s, 3, bout, (float*)d_out, N, O, O / 64, 0);
    }
}

// Round 5
// 454.478 us; speedup vs baseline: 1.8816x; 1.0207x over previous
//
#include <hip/hip_runtime.h>
#include <hip/hip_bf16.h>

#define KDIM 512

typedef short s16x8 __attribute__((ext_vector_type(8)));
typedef float f32x4 __attribute__((ext_vector_type(4)));
typedef unsigned short u16x8 __attribute__((ext_vector_type(8)));

static __device__ __forceinline__ float bf2f(unsigned short b) {
    union { unsigned int u; float f; } cv;
    cv.u = ((unsigned int)b) << 16;
    return cv.f;
}
static __device__ __forceinline__ unsigned short f2bf(float v) {
    __hip_bfloat16 h = __float2bfloat16(v);
    return *reinterpret_cast<unsigned short*>(&h);
}

// ---------------- CSR build ----------------

__global__ void deg_kernel(const int* __restrict__ dst, int* __restrict__ deg, int E) {
    int e = blockIdx.x * blockDim.x + threadIdx.x;
    if (e < E) atomicAdd(&deg[dst[e]], 1);
}

__global__ void scan_kernel(const int* __restrict__ deg, int* __restrict__ off, int n) {
    __shared__ int wsum[16];
    __shared__ int carry;
    int tid = threadIdx.x;
    int lane = tid & 63, wv = tid >> 6;
    if (tid == 0) carry = 0;
    __syncthreads();
    for (int start = 0; start < n; start += 1024) {
        int i = start + tid;
        int orig = (i < n) ? deg[i] : 0;
        int v = orig;
#pragma unroll
        for (int d = 1; d < 64; d <<= 1) {
            int t = __shfl_up(v, d, 64);
            if (lane >= d) v += t;
        }
        if (lane == 63) wsum[wv] = v;
        __syncthreads();
        int base = carry;
        if (wv == 0 && lane < 16) {
            int s = wsum[lane];
#pragma unroll
            for (int d = 1; d < 16; d <<= 1) {
                int t = __shfl_up(s, d, 64);
                if (lane >= d) s += t;
            }
            wsum[lane] = s;
            if (lane == 15) carry = base + s;
        }
        __syncthreads();
        int wpre = (wv == 0) ? 0 : wsum[wv - 1];
        if (i < n) off[i] = base + wpre + v - orig;   // exclusive
        __syncthreads();
    }
    if (tid == 0) off[n] = carry;
}

__global__ void fill_csr(const int* __restrict__ src, const int* __restrict__ dst,
                         const int* __restrict__ off, int* __restrict__ cursor,
                         int* __restrict__ csr_src, int E) {
    int e = blockIdx.x * blockDim.x + threadIdx.x;
    if (e < E) {
        int d = dst[e];
        int p = atomicAdd(&cursor[d], 1);
        csr_src[off[d] + p] = src[e];
    }
}

// ---------------- conversions ----------------

__global__ void conv_x_kernel(const float* __restrict__ x,
                              unsigned short* __restrict__ hi,
                              unsigned short* __restrict__ lo, int total4) {
    int i = blockIdx.x * blockDim.x + threadIdx.x;
    if (i >= total4) return;
    float4 v = *(const float4*)(x + (size_t)i * 4);
    ushort4 h, l;
    h.x = f2bf(v.x); l.x = f2bf(v.x - bf2f(h.x));
    h.y = f2bf(v.y); l.y = f2bf(v.y - bf2f(h.y));
    h.z = f2bf(v.z); l.z = f2bf(v.z - bf2f(h.z));
    h.w = f2bf(v.w); l.w = f2bf(v.w - bf2f(h.w));
    *(ushort4*)(hi + (size_t)i * 4) = h;
    *(ushort4*)(lo + (size_t)i * 4) = l;
}

// batched: 6 hidden-layer weight halves, W [512][512] -> W^T hi/lo [512][512]
struct WBatch {
    const float* w[6];
    unsigned short* thi[6];
    unsigned short* tlo[6];
};

__global__ void conv_w6(WBatch wb) {
    __shared__ float t[32][33];
    int li = blockIdx.z;
    const float* W = wb.w[li];
    unsigned short* Thi = wb.thi[li];
    unsigned short* Tlo = wb.tlo[li];
    int tx = threadIdx.x & 31, ty = threadIdx.x >> 5;
    int k0 = blockIdx.x * 32, n0 = blockIdx.y * 32;
#pragma unroll
    for (int j = 0; j < 4; ++j) {
        int r = ty + j * 8;
        t[r][tx] = W[(size_t)(k0 + r) * 512 + n0 + tx];
    }
    __syncthreads();
#pragma unroll
    for (int j = 0; j < 4; ++j) {
        int rn = ty + j * 8;
        float v = t[tx][rn];
        unsigned short h = f2bf(v);
        unsigned short l = f2bf(v - bf2f(h));
        size_t idx = (size_t)(n0 + rn) * KDIM + k0 + tx;
        Thi[idx] = h;
        Tlo[idx] = l;
    }
}

__global__ void conv_w_kernel(const float* __restrict__ W,
                              unsigned short* __restrict__ Thi,
                              unsigned short* __restrict__ Tlo, int Nw) {
    __shared__ float t[32][33];
    int tx = threadIdx.x & 31, ty = threadIdx.x >> 5;
    int k0 = blockIdx.x * 32, n0 = blockIdx.y * 32;
#pragma unroll
    for (int j = 0; j < 4; ++j) {
        int r = ty + j * 8;
        t[r][tx] = W[(size_t)(k0 + r) * Nw + n0 + tx];
    }
    __syncthreads();
#pragma unroll
    for (int j = 0; j < 4; ++j) {
        int rn = ty + j * 8;
        float v = t[tx][rn];
        unsigned short h = f2bf(v);
        unsigned short l = f2bf(v - bf2f(h));
        size_t idx = (size_t)(n0 + rn) * KDIM + k0 + tx;
        Thi[idx] = h;
        Tlo[idx] = l;
    }
}

// ---------------- MFMA GEMM over K-segments ----------------

struct Segs {
    const unsigned short* a[3];
    const unsigned short* b[3];
};

template<int BM, int BN>
__global__ __launch_bounds__(256) void gemm_mfma(
    Segs segs, int nseg, const float* __restrict__ bias,
    float* __restrict__ out, int M, int ldo, int NBY, int relu) {
    constexpr int FM = BM / 32;
    constexpr int FN = BN / 32;
    __shared__ unsigned short As[BM * 64];
    __shared__ unsigned short Bs[BN * 64];

    int tid = threadIdx.x;
    int lane = tid & 63;
    int wid = tid >> 6;

    // bijective XCD chunk map (m204)
    int nwg = gridDim.x;
    int q = nwg >> 3, rres = nwg & 7;
    int xcd = blockIdx.x & 7;
    int tile = (xcd < rres ? xcd * (q + 1) : rres * (q + 1) + (xcd - rres) * q)
             + (blockIdx.x >> 3);
    int rowBase = (tile / NBY) * BM;
    int colBase = (tile % NBY) * BN;

    int wm = (wid >> 1) * (BM / 2);
    int wn = (wid & 1) * (BN / 2);

    f32x4 acc[FM][FN] = {};

    int srow = lane >> 3;                       // 0..7
    int scol = ((lane & 7) ^ srow) * 8;         // pre-swizzled source chunk

    int nsteps = nseg * 8;
    for (int kt = 0; kt < nsteps; ++kt) {
        int seg = kt >> 3;
        int k0 = (kt & 7) * 64;
        const unsigned short* pa = segs.a[seg];
        const unsigned short* pb = segs.b[seg];

#pragma unroll
        for (int s = 0; s < BM / 32; ++s) {
            int r0 = wid * (BM / 4) + s * 8;
            int gr = rowBase + r0 + srow;
            if (gr >= M) gr = M - 1;
            const unsigned short* g = pa + (size_t)gr * KDIM + k0 + scol;
            __builtin_amdgcn_global_load_lds(
                (const __attribute__((address_space(1))) unsigned int*)g,
                (__attribute__((address_space(3))) unsigned int*)&As[r0 * 64],
                16, 0, 0);
        }
#pragma unroll
        for (int s = 0; s < BN / 32; ++s) {
            int r0 = wid * (BN / 4) + s * 8;
            const unsigned short* g = pb + (size_t)(colBase + r0 + srow) * KDIM + k0 + scol;
            __builtin_amdgcn_global_load_lds(
                (const __attribute__((address_space(1))) unsigned int*)g,
                (__attribute__((address_space(3))) unsigned int*)&Bs[r0 * 64],
                16, 0, 0);
        }
        __syncthreads();

#pragma unroll
        for (int kk = 0; kk < 2; ++kk) {
            s16x8 aF[FM], bF[FN];
#pragma unroll
            for (int m = 0; m < FM; ++m) {
                int rr = wm + m * 16 + (lane & 15);
                int slot = ((kk << 2) + (lane >> 4)) ^ (lane & 7);
                aF[m] = *(const s16x8*)&As[rr * 64 + slot * 8];
            }
#pragma unroll
            for (int n = 0; n < FN; ++n) {
                int rn = wn + n * 16 + (lane & 15);
                int slot = ((kk << 2) + (lane >> 4)) ^ (lane & 7);
                bF[n] = *(const s16x8*)&Bs[rn * 64 + slot * 8];
            }
#pragma unroll
            for (int m = 0; m < FM; ++m)
#pragma unroll
                for (int n = 0; n < FN; ++n)
                    acc[m][n] = __builtin_amdgcn_mfma_f32_16x16x32_bf16(aF[m], bF[n], acc[m][n], 0, 0, 0);
        }
        __syncthreads();
    }

#pragma unroll
    for (int n = 0; n < FN; ++n) {
        int col = colBase + wn + n * 16 + (lane & 15);
        float bb = bias ? bias[col] : 0.0f;
#pragma unroll
        for (int m = 0; m < FM; ++m) {
            int row0 = rowBase + wm + m * 16 + (lane >> 4) * 4;
#pragma unroll
            for (int r = 0; r < 4; ++r) {
                int row = row0 + r;
                if (row < M) {
                    float v = acc[m][n][r] + bb;
                    if (relu) v = fmaxf(v, 0.f);
                    out[(size_t)row * ldo + col] = v;
                }
            }
        }
    }
}

// ---------------- column-sliced, XCD-pinned gather epilogue ----------------
// slice = blockIdx.x & 7 -> XCD c (round-robin dispatch). Each XCD touches only
// its 64-col slice of P1 (10000*64*4 = 2.56 MB, L2-resident).
// next = relu(mean_gather(P[:, :512]) + P[:, 512:1024] + b), hi/lo planes.

__global__ __launch_bounds__(256) void gather_slice(
    const float* __restrict__ P, const int* __restrict__ off,
    const int* __restrict__ csr_src, const float* __restrict__ bias,
    unsigned short* __restrict__ ohi, unsigned short* __restrict__ olo, int n) {
    int slice = blockIdx.x & 7;
    int chunk = blockIdx.x >> 3;
    int wv = threadIdx.x >> 6;
    int lane = threadIdx.x & 63;
    int c = slice * 64 + lane;                 // column 0..511
    float bb = bias[c];
    int node0 = chunk * 32 + wv * 8;

    for (int i = 0; i < 8; ++i) {
        int node = node0 + i;
        if (node >= n) return;
        int beg = off[node], end = off[node + 1];
        float acc = 0.f;
        int e = beg;
        for (; e + 4 <= end; e += 4) {
            int s0 = csr_src[e + 0];
            int s1 = csr_src[e + 1];
            int s2 = csr_src[e + 2];
            int s3 = csr_src[e + 3];
            float v0 = P[(size_t)s0 * 1024 + c];
            float v1 = P[(size_t)s1 * 1024 + c];
            float v2 = P[(size_t)s2 * 1024 + c];
            float v3 = P[(size_t)s3 * 1024 + c];
            acc += v0 + v1 + v2 + v3;
        }
        for (; e < end; ++e) acc += P[(size_t)csr_src[e] * 1024 + c];
        float inv = 1.0f / fmaxf((float)(end - beg), 1.0f);
        float v = acc * inv + P[(size_t)node * 1024 + 512 + c] + bb;
        v = fmaxf(v, 0.f);
        unsigned short h = f2bf(v);
        ohi[(size_t)node * KDIM + c] = h;
        olo[(size_t)node * KDIM + c] = f2bf(v - bf2f(h));
    }
}

// ---------------- launch ----------------

extern "C" void kernel_launch(void* const* d_in, const int* in_sizes, int n_in,
                              void* d_out, int out_size, void* d_ws, size_t ws_size,
                              hipStream_t stream) {
    const float* x    = (const float*)d_in[0];
    const int*   ei   = (const int*)d_in[1];
    const float* wl0  = (const float*)d_in[2];
    const float* bl0  = (const float*)d_in[3];
    const float* wr0  = (const float*)d_in[4];
    const float* wl1  = (const float*)d_in[5];
    const float* bl1  = (const float*)d_in[6];
    const float* wr1  = (const float*)d_in[7];
    const float* wl2  = (const float*)d_in[8];
    const float* bl2  = (const float*)d_in[9];
    const float* wr2  = (const float*)d_in[10];
    const float* wout = (const float*)d_in[11];
    const float* bout = (const float*)d_in[12];

    int N = in_sizes[0] / KDIM;     // 10000 nodes
    int E = in_sizes[1] / 2;        // 160000 edges
    int O = in_sizes[12];           // 128

    const int* src = ei;
    const int* dst = ei + E;

    char* ws = (char*)d_ws;
    auto align = [](size_t o) { return (o + 255) & ~(size_t)255; };
    size_t o = 0;
    int* deg     = (int*)(ws + o); o = align(o + (size_t)N * 4);
    int* cursor  = (int*)(ws + o); o = align(o + (size_t)N * 4);
    int* off     = (int*)(ws + o); o = align(o + (size_t)(N + 1) * 4);
    int* csr_src = (int*)(ws + o); o = align(o + (size_t)E * 4);

    size_t planeB = (size_t)N * KDIM * 2;
    unsigned short* x_hi = (unsigned short*)(ws + o); o = align(o + planeB);
    unsigned short* x_lo = (unsigned short*)(ws + o); o = align(o + planeB);
    unsigned short* a_hi = (unsigned short*)(ws + o); o = align(o + planeB);
    unsigned short* a_lo = (unsigned short*)(ws + o); o = align(o + planeB);
    float* P = (float*)(ws + o); o = align(o + (size_t)N * 1024 * 4);

    size_t whB = (size_t)1024 * KDIM * 2;
    unsigned short* WThi[3];
    unsigned short* WTlo[3];
    for (int i = 0; i < 3; ++i) {
        WThi[i] = (unsigned short*)(ws + o); o = align(o + whB);
        WTlo[i] = (unsigned short*)(ws + o); o = align(o + whB);
    }
    size_t woB = (size_t)O * KDIM * 2;
    unsigned short* WoThi = (unsigned short*)(ws + o); o = align(o + woB);
    unsigned short* WoTlo = (unsigned short*)(ws + o); o = align(o + woB);

    hipMemsetAsync(deg, 0, (size_t)N * 4, stream);
    hipMemsetAsync(cursor, 0, (size_t)N * 4, stream);

    deg_kernel<<<(E + 255) / 256, 256, 0, stream>>>(dst, deg, E);
    scan_kernel<<<1, 1024, 0, stream>>>(deg, off, N);
    fill_csr<<<(E + 255) / 256, 256, 0, stream>>>(src, dst, off, cursor, csr_src, E);

    conv_x_kernel<<<(N * KDIM / 4 + 255) / 256, 256, 0, stream>>>(x, x_hi, x_lo, N * KDIM / 4);

    const float* wl[3] = {wl0, wl1, wl2};
    const float* wr[3] = {wr0, wr1, wr2};
    {
        WBatch wb;
        for (int i = 0; i < 3; ++i) {
            wb.w[i * 2 + 0] = wl[i];
            wb.thi[i * 2 + 0] = WThi[i];
            wb.tlo[i * 2 + 0] = WTlo[i];
            wb.w[i * 2 + 1] = wr[i];
            wb.thi[i * 2 + 1] = WThi[i] + (size_t)512 * KDIM;
            wb.tlo[i * 2 + 1] = WTlo[i] + (size_t)512 * KDIM;
        }
        dim3 wgrid(16, 16, 6);
        conv_w6<<<wgrid, 256, 0, stream>>>(wb);
    }
    dim3 wogrid(16, O / 32);
    conv_w_kernel<<<wogrid, 256, 0, stream>>>(wout, WoThi, WoTlo, O);

    int nwgH = ((N + 63) / 64) * 8;          // 64x128 tiles: 157 * 8 = 1256
    int gatherBlocks = ((N + 31) / 32) * 8;  // 313 chunks * 8 slices = 2504
    const float* bl[3] = {bl0, bl1, bl2};

    unsigned short* inHi[4] = {x_hi, a_hi, x_hi, a_hi};
    unsigned short* inLo[4] = {x_lo, a_lo, x_lo, a_lo};

    for (int i = 0; i < 3; ++i) {
        Segs s = {{inHi[i], inLo[i], inHi[i]}, {WThi[i], WThi[i], WTlo[i]}};
        gemm_mfma<64, 128><<<nwgH, 256, 0, stream>>>(s, 3, nullptr, P, N, 1024, 8, 0);
        gather_slice<<<gatherBlocks, 256, 0, stream>>>(P, off, csr_src, bl[i], inHi[i + 1], inLo[i + 1], N);
    }

    // output projection: [N,512] @ [512,128] + bout
    {
        Segs s = {{inHi[3], inLo[3], inHi[3]}, {WoThi, WoThi, WoTlo}};
        int nwgO = ((N + 63) / 64) * (O / 64);   // 157 * 2 = 314
        gemm_mfma<64, 64><<<nwgO, 256, 0, stream>>>(s, 3, bout, (float*)d_out, N, O, O / 64, 0);
    }
}

// Round 6
// 396.310 us; speedup vs baseline: 2.1577x; 1.1468x over previous
//
#include <hip/hip_runtime.h>
#include <hip/hip_bf16.h>

#define KDIM 512

typedef short s16x8 __attribute__((ext_vector_type(8)));
typedef float f32x4 __attribute__((ext_vector_type(4)));
typedef unsigned short u16x8 __attribute__((ext_vector_type(8)));

static __device__ __forceinline__ float bf2f(unsigned short b) {
    union { unsigned int u; float f; } cv;
    cv.u = ((unsigned int)b) << 16;
    return cv.f;
}
static __device__ __forceinline__ unsigned short f2bf(float v) {
    __hip_bfloat16 h = __float2bfloat16(v);
    return *reinterpret_cast<unsigned short*>(&h);
}

// ---------------- CSR build ----------------

__global__ void deg_kernel(const int* __restrict__ dst, int* __restrict__ deg, int E) {
    int e = blockIdx.x * blockDim.x + threadIdx.x;
    if (e < E) atomicAdd(&deg[dst[e]], 1);
}

__global__ void scan_kernel(const int* __restrict__ deg, int* __restrict__ off, int n) {
    __shared__ int wsum[16];
    __shared__ int carry;
    int tid = threadIdx.x;
    int lane = tid & 63, wv = tid >> 6;
    if (tid == 0) carry = 0;
    __syncthreads();
    for (int start = 0; start < n; start += 1024) {
        int i = start + tid;
        int orig = (i < n) ? deg[i] : 0;
        int v = orig;
#pragma unroll
        for (int d = 1; d < 64; d <<= 1) {
            int t = __shfl_up(v, d, 64);
            if (lane >= d) v += t;
        }
        if (lane == 63) wsum[wv] = v;
        __syncthreads();
        int base = carry;
        if (wv == 0 && lane < 16) {
            int s = wsum[lane];
#pragma unroll
            for (int d = 1; d < 16; d <<= 1) {
                int t = __shfl_up(s, d, 64);
                if (lane >= d) s += t;
            }
            wsum[lane] = s;
            if (lane == 15) carry = base + s;
        }
        __syncthreads();
        int wpre = (wv == 0) ? 0 : wsum[wv - 1];
        if (i < n) off[i] = base + wpre + v - orig;   // exclusive
        __syncthreads();
    }
    if (tid == 0) off[n] = carry;
}

__global__ void fill_csr(const int* __restrict__ src, const int* __restrict__ dst,
                         const int* __restrict__ off, int* __restrict__ cursor,
                         int* __restrict__ csr_src, int E) {
    int e = blockIdx.x * blockDim.x + threadIdx.x;
    if (e < E) {
        int d = dst[e];
        int p = atomicAdd(&cursor[d], 1);
        csr_src[off[d] + p] = src[e];
    }
}

// ---------------- conversions ----------------

__global__ void conv_x_kernel(const float* __restrict__ x,
                              unsigned short* __restrict__ hi,
                              unsigned short* __restrict__ lo, int total4) {
    int i = blockIdx.x * blockDim.x + threadIdx.x;
    if (i >= total4) return;
    float4 v = *(const float4*)(x + (size_t)i * 4);
    ushort4 h, l;
    h.x = f2bf(v.x); l.x = f2bf(v.x - bf2f(h.x));
    h.y = f2bf(v.y); l.y = f2bf(v.y - bf2f(h.y));
    h.z = f2bf(v.z); l.z = f2bf(v.z - bf2f(h.z));
    h.w = f2bf(v.w); l.w = f2bf(v.w - bf2f(h.w));
    *(ushort4*)(hi + (size_t)i * 4) = h;
    *(ushort4*)(lo + (size_t)i * 4) = l;
}

// batched: 6 hidden-layer weight halves, W [512][512] -> W^T hi/lo [512][512]
struct WBatch {
    const float* w[6];
    unsigned short* thi[6];
    unsigned short* tlo[6];
};

__global__ void conv_w6(WBatch wb) {
    __shared__ float t[32][33];
    int li = blockIdx.z;
    const float* W = wb.w[li];
    unsigned short* Thi = wb.thi[li];
    unsigned short* Tlo = wb.tlo[li];
    int tx = threadIdx.x & 31, ty = threadIdx.x >> 5;
    int k0 = blockIdx.x * 32, n0 = blockIdx.y * 32;
#pragma unroll
    for (int j = 0; j < 4; ++j) {
        int r = ty + j * 8;
        t[r][tx] = W[(size_t)(k0 + r) * 512 + n0 + tx];
    }
    __syncthreads();
#pragma unroll
    for (int j = 0; j < 4; ++j) {
        int rn = ty + j * 8;
        float v = t[tx][rn];
        unsigned short h = f2bf(v);
        unsigned short l = f2bf(v - bf2f(h));
        size_t idx = (size_t)(n0 + rn) * KDIM + k0 + tx;
        Thi[idx] = h;
        Tlo[idx] = l;
    }
}

__global__ void conv_w_kernel(const float* __restrict__ W,
                              unsigned short* __restrict__ Thi,
                              unsigned short* __restrict__ Tlo, int Nw) {
    __shared__ float t[32][33];
    int tx = threadIdx.x & 31, ty = threadIdx.x >> 5;
    int k0 = blockIdx.x * 32, n0 = blockIdx.y * 32;
#pragma unroll
    for (int j = 0; j < 4; ++j) {
        int r = ty + j * 8;
        t[r][tx] = W[(size_t)(k0 + r) * Nw + n0 + tx];
    }
    __syncthreads();
#pragma unroll
    for (int j = 0; j < 4; ++j) {
        int rn = ty + j * 8;
        float v = t[tx][rn];
        unsigned short h = f2bf(v);
        unsigned short l = f2bf(v - bf2f(h));
        size_t idx = (size_t)(n0 + rn) * KDIM + k0 + tx;
        Thi[idx] = h;
        Tlo[idx] = l;
    }
}

// ---------------- MFMA GEMM over K-segments ----------------

struct Segs {
    const unsigned short* a[3];
    const unsigned short* b[3];
};

template<int BM, int BN>
__global__ __launch_bounds__(256) void gemm_mfma(
    Segs segs, int nseg, const float* __restrict__ bias,
    float* __restrict__ out, int M, int ldo, int NBY, int relu) {
    constexpr int FM = BM / 32;
    constexpr int FN = BN / 32;
    __shared__ unsigned short As[BM * 64];
    __shared__ unsigned short Bs[BN * 64];

    int tid = threadIdx.x;
    int lane = tid & 63;
    int wid = tid >> 6;

    // bijective XCD chunk map (m204)
    int nwg = gridDim.x;
    int q = nwg >> 3, rres = nwg & 7;
    int xcd = blockIdx.x & 7;
    int tile = (xcd < rres ? xcd * (q + 1) : rres * (q + 1) + (xcd - rres) * q)
             + (blockIdx.x >> 3);
    int rowBase = (tile / NBY) * BM;
    int colBase = (tile % NBY) * BN;

    int wm = (wid >> 1) * (BM / 2);
    int wn = (wid & 1) * (BN / 2);

    f32x4 acc[FM][FN] = {};

    int srow = lane >> 3;                       // 0..7
    int scol = ((lane & 7) ^ srow) * 8;         // pre-swizzled source chunk

    int nsteps = nseg * 8;
    for (int kt = 0; kt < nsteps; ++kt) {
        int seg = kt >> 3;
        int k0 = (kt & 7) * 64;
        const unsigned short* pa = segs.a[seg];
        const unsigned short* pb = segs.b[seg];

#pragma unroll
        for (int s = 0; s < BM / 32; ++s) {
            int r0 = wid * (BM / 4) + s * 8;
            int gr = rowBase + r0 + srow;
            if (gr >= M) gr = M - 1;
            const unsigned short* g = pa + (size_t)gr * KDIM + k0 + scol;
            __builtin_amdgcn_global_load_lds(
                (const __attribute__((address_space(1))) unsigned int*)g,
                (__attribute__((address_space(3))) unsigned int*)&As[r0 * 64],
                16, 0, 0);
        }
#pragma unroll
        for (int s = 0; s < BN / 32; ++s) {
            int r0 = wid * (BN / 4) + s * 8;
            const unsigned short* g = pb + (size_t)(colBase + r0 + srow) * KDIM + k0 + scol;
            __builtin_amdgcn_global_load_lds(
                (const __attribute__((address_space(1))) unsigned int*)g,
                (__attribute__((address_space(3))) unsigned int*)&Bs[r0 * 64],
                16, 0, 0);
        }
        __syncthreads();

#pragma unroll
        for (int kk = 0; kk < 2; ++kk) {
            s16x8 aF[FM], bF[FN];
#pragma unroll
            for (int m = 0; m < FM; ++m) {
                int rr = wm + m * 16 + (lane & 15);
                int slot = ((kk << 2) + (lane >> 4)) ^ (lane & 7);
                aF[m] = *(const s16x8*)&As[rr * 64 + slot * 8];
            }
#pragma unroll
            for (int n = 0; n < FN; ++n) {
                int rn = wn + n * 16 + (lane & 15);
                int slot = ((kk << 2) + (lane >> 4)) ^ (lane & 7);
                bF[n] = *(const s16x8*)&Bs[rn * 64 + slot * 8];
            }
#pragma unroll
            for (int m = 0; m < FM; ++m)
#pragma unroll
                for (int n = 0; n < FN; ++n)
                    acc[m][n] = __builtin_amdgcn_mfma_f32_16x16x32_bf16(aF[m], bF[n], acc[m][n], 0, 0, 0);
        }
        __syncthreads();
    }

#pragma unroll
    for (int n = 0; n < FN; ++n) {
        int col = colBase + wn + n * 16 + (lane & 15);
        float bb = bias ? bias[col] : 0.0f;
#pragma unroll
        for (int m = 0; m < FM; ++m) {
            int row0 = rowBase + wm + m * 16 + (lane >> 4) * 4;
#pragma unroll
            for (int r = 0; r < 4; ++r) {
                int row = row0 + r;
                if (row < M) {
                    float v = acc[m][n][r] + bb;
                    if (relu) v = fmaxf(v, 0.f);
                    out[(size_t)row * ldo + col] = v;
                }
            }
        }
    }
}

// ---------------- column-sliced gather, 4-edge-parallel float4 lanes ----------------
// wave handles one (node, slice). lane = (edge_sub 0..3) x (col_quad 0..15).
// Each lane loads float4 for edge (beg + it*4 + edge_sub), cols c4..c4+3.
// Reduce the 4 edge groups via shfl_xor(16,32). XCD pin: slice = blockIdx & 7.

__global__ __launch_bounds__(256) void gather_slice(
    const float* __restrict__ P, const int* __restrict__ off,
    const int* __restrict__ csr_src, const float* __restrict__ bias,
    unsigned short* __restrict__ ohi, unsigned short* __restrict__ olo, int n) {
    int slice = blockIdx.x & 7;
    int chunk = blockIdx.x >> 3;
    int wv = threadIdx.x >> 6;
    int lane = threadIdx.x & 63;
    int node = chunk * 4 + wv;
    if (node >= n) return;

    int esub = lane >> 4;                  // 0..3 edge sub-lane
    int c4 = slice * 64 + (lane & 15) * 4; // absolute col quad base

    int beg = off[node], end = off[node + 1];
    float ax = 0.f, ay = 0.f, az = 0.f, aw = 0.f;
#pragma unroll 2
    for (int it = beg + esub; it < end; it += 4) {
        int s = csr_src[it];
        float4 v = *(const float4*)(P + (size_t)s * 1024 + c4);
        ax += v.x; ay += v.y; az += v.z; aw += v.w;
    }
    // combine the 4 edge groups (lanes differing in bits 4,5)
    ax += __shfl_xor(ax, 16, 64); ay += __shfl_xor(ay, 16, 64);
    az += __shfl_xor(az, 16, 64); aw += __shfl_xor(aw, 16, 64);
    ax += __shfl_xor(ax, 32, 64); ay += __shfl_xor(ay, 32, 64);
    az += __shfl_xor(az, 32, 64); aw += __shfl_xor(aw, 32, 64);

    if (esub == 0) {   // lanes 0..15 finalize + store
        float inv = 1.0f / fmaxf((float)(end - beg), 1.0f);
        float4 p2 = *(const float4*)(P + (size_t)node * 1024 + 512 + c4);
        float4 bb = *(const float4*)(bias + c4);
        float vals[4];
        vals[0] = ax * inv + p2.x + bb.x;
        vals[1] = ay * inv + p2.y + bb.y;
        vals[2] = az * inv + p2.z + bb.z;
        vals[3] = aw * inv + p2.w + bb.w;
        ushort4 h4, l4;
        {
            float v0 = fmaxf(vals[0], 0.f); h4.x = f2bf(v0); l4.x = f2bf(v0 - bf2f(h4.x));
            float v1 = fmaxf(vals[1], 0.f); h4.y = f2bf(v1); l4.y = f2bf(v1 - bf2f(h4.y));
            float v2 = fmaxf(vals[2], 0.f); h4.z = f2bf(v2); l4.z = f2bf(v2 - bf2f(h4.z));
            float v3 = fmaxf(vals[3], 0.f); h4.w = f2bf(v3); l4.w = f2bf(v3 - bf2f(h4.w));
        }
        *(ushort4*)(ohi + (size_t)node * KDIM + c4) = h4;
        *(ushort4*)(olo + (size_t)node * KDIM + c4) = l4;
    }
}

// ---------------- launch ----------------

extern "C" void kernel_launch(void* const* d_in, const int* in_sizes, int n_in,
                              void* d_out, int out_size, void* d_ws, size_t ws_size,
                              hipStream_t stream) {
    const float* x    = (const float*)d_in[0];
    const int*   ei   = (const int*)d_in[1];
    const float* wl0  = (const float*)d_in[2];
    const float* bl0  = (const float*)d_in[3];
    const float* wr0  = (const float*)d_in[4];
    const float* wl1  = (const float*)d_in[5];
    const float* bl1  = (const float*)d_in[6];
    const float* wr1  = (const float*)d_in[7];
    const float* wl2  = (const float*)d_in[8];
    const float* bl2  = (const float*)d_in[9];
    const float* wr2  = (const float*)d_in[10];
    const float* wout = (const float*)d_in[11];
    const float* bout = (const float*)d_in[12];

    int N = in_sizes[0] / KDIM;     // 10000 nodes
    int E = in_sizes[1] / 2;        // 160000 edges
    int O = in_sizes[12];           // 128

    const int* src = ei;
    const int* dst = ei + E;

    char* ws = (char*)d_ws;
    auto align = [](size_t o) { return (o + 255) & ~(size_t)255; };
    size_t o = 0;
    int* deg     = (int*)(ws + o); o = align(o + (size_t)N * 4);
    int* cursor  = (int*)(ws + o); o = align(o + (size_t)N * 4);
    int* off     = (int*)(ws + o); o = align(o + (size_t)(N + 1) * 4);
    int* csr_src = (int*)(ws + o); o = align(o + (size_t)E * 4);

    size_t planeB = (size_t)N * KDIM * 2;
    unsigned short* x_hi = (unsigned short*)(ws + o); o = align(o + planeB);
    unsigned short* x_lo = (unsigned short*)(ws + o); o = align(o + planeB);
    unsigned short* a_hi = (unsigned short*)(ws + o); o = align(o + planeB);
    unsigned short* a_lo = (unsigned short*)(ws + o); o = align(o + planeB);
    float* P = (float*)(ws + o); o = align(o + (size_t)N * 1024 * 4);

    size_t whB = (size_t)1024 * KDIM * 2;
    unsigned short* WThi[3];
    unsigned short* WTlo[3];
    for (int i = 0; i < 3; ++i) {
        WThi[i] = (unsigned short*)(ws + o); o = align(o + whB);
        WTlo[i] = (unsigned short*)(ws + o); o = align(o + whB);
    }
    size_t woB = (size_t)O * KDIM * 2;
    unsigned short* WoThi = (unsigned short*)(ws + o); o = align(o + woB);
    unsigned short* WoTlo = (unsigned short*)(ws + o); o = align(o + woB);

    hipMemsetAsync(deg, 0, (size_t)N * 4, stream);
    hipMemsetAsync(cursor, 0, (size_t)N * 4, stream);

    deg_kernel<<<(E + 255) / 256, 256, 0, stream>>>(dst, deg, E);
    scan_kernel<<<1, 1024, 0, stream>>>(deg, off, N);
    fill_csr<<<(E + 255) / 256, 256, 0, stream>>>(src, dst, off, cursor, csr_src, E);

    conv_x_kernel<<<(N * KDIM / 4 + 255) / 256, 256, 0, stream>>>(x, x_hi, x_lo, N * KDIM / 4);

    const float* wl[3] = {wl0, wl1, wl2};
    const float* wr[3] = {wr0, wr1, wr2};
    {
        WBatch wb;
        for (int i = 0; i < 3; ++i) {
            wb.w[i * 2 + 0] = wl[i];
            wb.thi[i * 2 + 0] = WThi[i];
            wb.tlo[i * 2 + 0] = WTlo[i];
            wb.w[i * 2 + 1] = wr[i];
            wb.thi[i * 2 + 1] = WThi[i] + (size_t)512 * KDIM;
            wb.tlo[i * 2 + 1] = WTlo[i] + (size_t)512 * KDIM;
        }
        dim3 wgrid(16, 16, 6);
        conv_w6<<<wgrid, 256, 0, stream>>>(wb);
    }
    dim3 wogrid(16, O / 32);
    conv_w_kernel<<<wogrid, 256, 0, stream>>>(wout, WoThi, WoTlo, O);

    int nwgH = ((N + 63) / 64) * 8;            // 64x128 tiles: 157 * 8 = 1256
    int gatherBlocks = ((N + 3) / 4) * 8;      // 2500 chunks * 8 slices = 20000
    const float* bl[3] = {bl0, bl1, bl2};

    unsigned short* inHi[4] = {x_hi, a_hi, x_hi, a_hi};
    unsigned short* inLo[4] = {x_lo, a_lo, x_lo, a_lo};

    for (int i = 0; i < 3; ++i) {
        Segs s = {{inHi[i], inLo[i], inHi[i]}, {WThi[i], WThi[i], WTlo[i]}};
        gemm_mfma<64, 128><<<nwgH, 256, 0, stream>>>(s, 3, nullptr, P, N, 1024, 8, 0);
        gather_slice<<<gatherBlocks, 256, 0, stream>>>(P, off, csr_src, bl[i], inHi[i + 1], inLo[i + 1], N);
    }

    // output projection: [N,512] @ [512,128] + bout
    {
        Segs s = {{inHi[3], inLo[3], inHi[3]}, {WoThi, WoThi, WoTlo}};
        int nwgO = ((N + 63) / 64) * (O / 64);   // 157 * 2 = 314
        gemm_mfma<64, 64><<<nwgO, 256, 0, stream>>>(s, 3, bout, (float*)d_out, N, O, O / 64, 0);
    }
}

// Round 7
// 336.974 us; speedup vs baseline: 2.5377x; 1.1761x over previous
//
#include <hip/hip_runtime.h>
#include <hip/hip_bf16.h>

#define KDIM 512

typedef short s16x8 __attribute__((ext_vector_type(8)));
typedef float f32x4 __attribute__((ext_vector_type(4)));
typedef unsigned short u16x8 __attribute__((ext_vector_type(8)));

static __device__ __forceinline__ float bf2f(unsigned short b) {
    union { unsigned int u; float f; } cv;
    cv.u = ((unsigned int)b) << 16;
    return cv.f;
}
static __device__ __forceinline__ unsigned short f2bf(float v) {
    __hip_bfloat16 h = __float2bfloat16(v);
    return *reinterpret_cast<unsigned short*>(&h);
}

// ---------------- CSR build ----------------

__global__ void deg_kernel(const int* __restrict__ dst, int* __restrict__ deg, int E) {
    int e = blockIdx.x * blockDim.x + threadIdx.x;
    if (e < E) atomicAdd(&deg[dst[e]], 1);
}

__global__ void scan_kernel(const int* __restrict__ deg, int* __restrict__ off, int n) {
    __shared__ int wsum[16];
    __shared__ int carry;
    int tid = threadIdx.x;
    int lane = tid & 63, wv = tid >> 6;
    if (tid == 0) carry = 0;
    __syncthreads();
    for (int start = 0; start < n; start += 1024) {
        int i = start + tid;
        int orig = (i < n) ? deg[i] : 0;
        int v = orig;
#pragma unroll
        for (int d = 1; d < 64; d <<= 1) {
            int t = __shfl_up(v, d, 64);
            if (lane >= d) v += t;
        }
        if (lane == 63) wsum[wv] = v;
        __syncthreads();
        int base = carry;
        if (wv == 0 && lane < 16) {
            int s = wsum[lane];
#pragma unroll
            for (int d = 1; d < 16; d <<= 1) {
                int t = __shfl_up(s, d, 64);
                if (lane >= d) s += t;
            }
            wsum[lane] = s;
            if (lane == 15) carry = base + s;
        }
        __syncthreads();
        int wpre = (wv == 0) ? 0 : wsum[wv - 1];
        if (i < n) off[i] = base + wpre + v - orig;   // exclusive
        __syncthreads();
    }
    if (tid == 0) off[n] = carry;
}

__global__ void fill_csr(const int* __restrict__ src, const int* __restrict__ dst,
                         const int* __restrict__ off, int* __restrict__ cursor,
                         int* __restrict__ csr_src, int E) {
    int e = blockIdx.x * blockDim.x + threadIdx.x;
    if (e < E) {
        int d = dst[e];
        int p = atomicAdd(&cursor[d], 1);
        csr_src[off[d] + p] = src[e];
    }
}

// ---------------- conversions ----------------

// x fp32 -> single bf16 plane
__global__ void conv_x_kernel(const float* __restrict__ x,
                              unsigned short* __restrict__ hi, int total4) {
    int i = blockIdx.x * blockDim.x + threadIdx.x;
    if (i >= total4) return;
    float4 v = *(const float4*)(x + (size_t)i * 4);
    ushort4 h;
    h.x = f2bf(v.x);
    h.y = f2bf(v.y);
    h.z = f2bf(v.z);
    h.w = f2bf(v.w);
    *(ushort4*)(hi + (size_t)i * 4) = h;
}

// batched: 6 hidden-layer weight halves, W [512][512] -> W^T hi/lo [512][512]
struct WBatch {
    const float* w[6];
    unsigned short* thi[6];
    unsigned short* tlo[6];
};

__global__ void conv_w6(WBatch wb) {
    __shared__ float t[32][33];
    int li = blockIdx.z;
    const float* W = wb.w[li];
    unsigned short* Thi = wb.thi[li];
    unsigned short* Tlo = wb.tlo[li];
    int tx = threadIdx.x & 31, ty = threadIdx.x >> 5;
    int k0 = blockIdx.x * 32, n0 = blockIdx.y * 32;
#pragma unroll
    for (int j = 0; j < 4; ++j) {
        int r = ty + j * 8;
        t[r][tx] = W[(size_t)(k0 + r) * 512 + n0 + tx];
    }
    __syncthreads();
#pragma unroll
    for (int j = 0; j < 4; ++j) {
        int rn = ty + j * 8;
        float v = t[tx][rn];
        unsigned short h = f2bf(v);
        unsigned short l = f2bf(v - bf2f(h));
        size_t idx = (size_t)(n0 + rn) * KDIM + k0 + tx;
        Thi[idx] = h;
        Tlo[idx] = l;
    }
}

__global__ void conv_w_kernel(const float* __restrict__ W,
                              unsigned short* __restrict__ Thi,
                              unsigned short* __restrict__ Tlo, int Nw) {
    __shared__ float t[32][33];
    int tx = threadIdx.x & 31, ty = threadIdx.x >> 5;
    int k0 = blockIdx.x * 32, n0 = blockIdx.y * 32;
#pragma unroll
    for (int j = 0; j < 4; ++j) {
        int r = ty + j * 8;
        t[r][tx] = W[(size_t)(k0 + r) * Nw + n0 + tx];
    }
    __syncthreads();
#pragma unroll
    for (int j = 0; j < 4; ++j) {
        int rn = ty + j * 8;
        float v = t[tx][rn];
        unsigned short h = f2bf(v);
        unsigned short l = f2bf(v - bf2f(h));
        size_t idx = (size_t)(n0 + rn) * KDIM + k0 + tx;
        Thi[idx] = h;
        Tlo[idx] = l;
    }
}

// ---------------- MFMA GEMM over K-segments ----------------
// C = sum_s A_s @ B_s^T. OUTBF: write bf16 (no bias/relu, gather does那); else fp32 +bias.

struct Segs {
    const unsigned short* a[2];
    const unsigned short* b[2];
};

template<int BM, int BN, bool OUTBF>
__global__ __launch_bounds__(256) void gemm_mfma(
    Segs segs, int nseg, const float* __restrict__ bias,
    float* __restrict__ outF, unsigned short* __restrict__ outB,
    int M, int ldo, int NBY, int relu) {
    constexpr int FM = BM / 32;
    constexpr int FN = BN / 32;
    __shared__ unsigned short As[BM * 64];
    __shared__ unsigned short Bs[BN * 64];

    int tid = threadIdx.x;
    int lane = tid & 63;
    int wid = tid >> 6;

    // bijective XCD chunk map (m204)
    int nwg = gridDim.x;
    int q = nwg >> 3, rres = nwg & 7;
    int xcd = blockIdx.x & 7;
    int tile = (xcd < rres ? xcd * (q + 1) : rres * (q + 1) + (xcd - rres) * q)
             + (blockIdx.x >> 3);
    int rowBase = (tile / NBY) * BM;
    int colBase = (tile % NBY) * BN;

    int wm = (wid >> 1) * (BM / 2);
    int wn = (wid & 1) * (BN / 2);

    f32x4 acc[FM][FN] = {};

    int srow = lane >> 3;                       // 0..7
    int scol = ((lane & 7) ^ srow) * 8;         // pre-swizzled source chunk

    int nsteps = nseg * 8;
    for (int kt = 0; kt < nsteps; ++kt) {
        int seg = kt >> 3;
        int k0 = (kt & 7) * 64;
        const unsigned short* pa = segs.a[seg];
        const unsigned short* pb = segs.b[seg];

#pragma unroll
        for (int s = 0; s < BM / 32; ++s) {
            int r0 = wid * (BM / 4) + s * 8;
            int gr = rowBase + r0 + srow;
            if (gr >= M) gr = M - 1;
            const unsigned short* g = pa + (size_t)gr * KDIM + k0 + scol;
            __builtin_amdgcn_global_load_lds(
                (const __attribute__((address_space(1))) unsigned int*)g,
                (__attribute__((address_space(3))) unsigned int*)&As[r0 * 64],
                16, 0, 0);
        }
#pragma unroll
        for (int s = 0; s < BN / 32; ++s) {
            int r0 = wid * (BN / 4) + s * 8;
            const unsigned short* g = pb + (size_t)(colBase + r0 + srow) * KDIM + k0 + scol;
            __builtin_amdgcn_global_load_lds(
                (const __attribute__((address_space(1))) unsigned int*)g,
                (__attribute__((address_space(3))) unsigned int*)&Bs[r0 * 64],
                16, 0, 0);
        }
        __syncthreads();

#pragma unroll
        for (int kk = 0; kk < 2; ++kk) {
            s16x8 aF[FM], bF[FN];
#pragma unroll
            for (int m = 0; m < FM; ++m) {
                int rr = wm + m * 16 + (lane & 15);
                int slot = ((kk << 2) + (lane >> 4)) ^ (lane & 7);
                aF[m] = *(const s16x8*)&As[rr * 64 + slot * 8];
            }
#pragma unroll
            for (int n = 0; n < FN; ++n) {
                int rn = wn + n * 16 + (lane & 15);
                int slot = ((kk << 2) + (lane >> 4)) ^ (lane & 7);
                bF[n] = *(const s16x8*)&Bs[rn * 64 + slot * 8];
            }
#pragma unroll
            for (int m = 0; m < FM; ++m)
#pragma unroll
                for (int n = 0; n < FN; ++n)
                    acc[m][n] = __builtin_amdgcn_mfma_f32_16x16x32_bf16(aF[m], bF[n], acc[m][n], 0, 0, 0);
        }
        __syncthreads();
    }

#pragma unroll
    for (int n = 0; n < FN; ++n) {
        int col = colBase + wn + n * 16 + (lane & 15);
        float bb = bias ? bias[col] : 0.0f;
#pragma unroll
        for (int m = 0; m < FM; ++m) {
            int row0 = rowBase + wm + m * 16 + (lane >> 4) * 4;
#pragma unroll
            for (int r = 0; r < 4; ++r) {
                int row = row0 + r;
                if (row < M) {
                    float v = acc[m][n][r] + bb;
                    if (relu) v = fmaxf(v, 0.f);
                    if (OUTBF) outB[(size_t)row * ldo + col] = f2bf(v);
                    else       outF[(size_t)row * ldo + col] = v;
                }
            }
        }
    }
}

// ---------------- column-sliced gather, 8-edge-parallel bf16 lanes ----------------
// P is bf16 [N][1024]. Wave handles one (node, slice). lane = (esub 0..7) x (coct 0..7);
// each lane loads u16x8 (16B) for edge (it), cols c8..c8+7; 8 edges in flight;
// node inner loop unrolled x2 (independent chains). Reduce esub via shfl_xor 8/16/32.
// out = bf16(relu(mean_gather(P[:,:512]) + P[:,512:] + b)), hi plane only.

__global__ __launch_bounds__(256) void gather_slice(
    const unsigned short* __restrict__ P, const int* __restrict__ off,
    const int* __restrict__ csr_src, const float* __restrict__ bias,
    unsigned short* __restrict__ ohi, int n) {
    int slice = blockIdx.x & 7;
    int chunk = blockIdx.x >> 3;
    int wv = threadIdx.x >> 6;
    int lane = threadIdx.x & 63;
    int node = chunk * 4 + wv;
    if (node >= n) return;

    int esub = lane >> 3;                  // 0..7 edge sub-lane
    int c8 = slice * 64 + (lane & 7) * 8;  // absolute col oct base

    int beg = off[node], end = off[node + 1];
    float a[8] = {0.f, 0.f, 0.f, 0.f, 0.f, 0.f, 0.f, 0.f};
    int it = beg + esub;
    for (; it + 8 < end; it += 16) {       // two independent chains
        int s0 = csr_src[it];
        int s1 = csr_src[it + 8];
        u16x8 v0 = *(const u16x8*)(P + (size_t)s0 * 1024 + c8);
        u16x8 v1 = *(const u16x8*)(P + (size_t)s1 * 1024 + c8);
#pragma unroll
        for (int j = 0; j < 8; ++j) a[j] += bf2f(v0[j]) + bf2f(v1[j]);
    }
    if (it < end) {
        int s0 = csr_src[it];
        u16x8 v0 = *(const u16x8*)(P + (size_t)s0 * 1024 + c8);
#pragma unroll
        for (int j = 0; j < 8; ++j) a[j] += bf2f(v0[j]);
    }
    // combine the 8 edge groups (lanes differing in bits 3,4,5)
#pragma unroll
    for (int j = 0; j < 8; ++j) {
        a[j] += __shfl_xor(a[j], 8);
        a[j] += __shfl_xor(a[j], 16);
        a[j] += __shfl_xor(a[j], 32);
    }

    if (esub == 0) {   // lanes 0..7 finalize + store 16B each
        float inv = 1.0f / fmaxf((float)(end - beg), 1.0f);
        u16x8 p2 = *(const u16x8*)(P + (size_t)node * 1024 + 512 + c8);
        const float4* pb = (const float4*)(bias + c8);
        float4 b0 = pb[0], b1 = pb[1];
        float bbv[8] = {b0.x, b0.y, b0.z, b0.w, b1.x, b1.y, b1.z, b1.w};
        u16x8 h8;
#pragma unroll
        for (int j = 0; j < 8; ++j) {
            float v = fmaxf(a[j] * inv + bf2f(p2[j]) + bbv[j], 0.f);
            h8[j] = f2bf(v);
        }
        *(u16x8*)(ohi + (size_t)node * KDIM + c8) = h8;
    }
}

// ---------------- launch ----------------

extern "C" void kernel_launch(void* const* d_in, const int* in_sizes, int n_in,
                              void* d_out, int out_size, void* d_ws, size_t ws_size,
                              hipStream_t stream) {
    const float* x    = (const float*)d_in[0];
    const int*   ei   = (const int*)d_in[1];
    const float* wl0  = (const float*)d_in[2];
    const float* bl0  = (const float*)d_in[3];
    const float* wr0  = (const float*)d_in[4];
    const float* wl1  = (const float*)d_in[5];
    const float* bl1  = (const float*)d_in[6];
    const float* wr1  = (const float*)d_in[7];
    const float* wl2  = (const float*)d_in[8];
    const float* bl2  = (const float*)d_in[9];
    const float* wr2  = (const float*)d_in[10];
    const float* wout = (const float*)d_in[11];
    const float* bout = (const float*)d_in[12];

    int N = in_sizes[0] / KDIM;     // 10000 nodes
    int E = in_sizes[1] / 2;        // 160000 edges
    int O = in_sizes[12];           // 128

    const int* src = ei;
    const int* dst = ei + E;

    char* ws = (char*)d_ws;
    auto align = [](size_t o) { return (o + 255) & ~(size_t)255; };
    size_t o = 0;
    int* deg     = (int*)(ws + o); o = align(o + (size_t)N * 4);
    int* cursor  = (int*)(ws + o); o = align(o + (size_t)N * 4);
    int* off     = (int*)(ws + o); o = align(o + (size_t)(N + 1) * 4);
    int* csr_src = (int*)(ws + o); o = align(o + (size_t)E * 4);

    size_t planeB = (size_t)N * KDIM * 2;
    unsigned short* x_hi = (unsigned short*)(ws + o); o = align(o + planeB);
    unsigned short* a_hi = (unsigned short*)(ws + o); o = align(o + planeB);
    unsigned short* P = (unsigned short*)(ws + o); o = align(o + (size_t)N * 1024 * 2);

    size_t whB = (size_t)1024 * KDIM * 2;
    unsigned short* WThi[3];
    unsigned short* WTlo[3];
    for (int i = 0; i < 3; ++i) {
        WThi[i] = (unsigned short*)(ws + o); o = align(o + whB);
        WTlo[i] = (unsigned short*)(ws + o); o = align(o + whB);
    }
    size_t woB = (size_t)O * KDIM * 2;
    unsigned short* WoThi = (unsigned short*)(ws + o); o = align(o + woB);
    unsigned short* WoTlo = (unsigned short*)(ws + o); o = align(o + woB);

    hipMemsetAsync(deg, 0, (size_t)N * 4, stream);
    hipMemsetAsync(cursor, 0, (size_t)N * 4, stream);

    deg_kernel<<<(E + 255) / 256, 256, 0, stream>>>(dst, deg, E);
    scan_kernel<<<1, 1024, 0, stream>>>(deg, off, N);
    fill_csr<<<(E + 255) / 256, 256, 0, stream>>>(src, dst, off, cursor, csr_src, E);

    conv_x_kernel<<<(N * KDIM / 4 + 255) / 256, 256, 0, stream>>>(x, x_hi, N * KDIM / 4);

    const float* wl[3] = {wl0, wl1, wl2};
    const float* wr[3] = {wr0, wr1, wr2};
    {
        WBatch wb;
        for (int i = 0; i < 3; ++i) {
            wb.w[i * 2 + 0] = wl[i];
            wb.thi[i * 2 + 0] = WThi[i];
            wb.tlo[i * 2 + 0] = WTlo[i];
            wb.w[i * 2 + 1] = wr[i];
            wb.thi[i * 2 + 1] = WThi[i] + (size_t)512 * KDIM;
            wb.tlo[i * 2 + 1] = WTlo[i] + (size_t)512 * KDIM;
        }
        dim3 wgrid(16, 16, 6);
        conv_w6<<<wgrid, 256, 0, stream>>>(wb);
    }
    dim3 wogrid(16, O / 32);
    conv_w_kernel<<<wogrid, 256, 0, stream>>>(wout, WoThi, WoTlo, O);

    int nwgH = ((N + 63) / 64) * 8;            // 64x128 tiles: 157 * 8 = 1256
    int gatherBlocks = ((N + 3) / 4) * 8;      // 2500 chunks * 8 slices = 20000
    const float* bl[3] = {bl0, bl1, bl2};

    unsigned short* inHi[4] = {x_hi, a_hi, x_hi, a_hi};

    for (int i = 0; i < 3; ++i) {
        // C = Ah @ Whi + Ah @ Wlo  (K = 1024), bf16 out
        Segs s = {{inHi[i], inHi[i]}, {WThi[i], WTlo[i]}};
        gemm_mfma<64, 128, true><<<nwgH, 256, 0, stream>>>(s, 2, nullptr, nullptr, P, N, 1024, 8, 0);
        gather_slice<<<gatherBlocks, 256, 0, stream>>>(P, off, csr_src, bl[i], inHi[i + 1], N);
    }

    // output projection: [N,512] @ [512,128] + bout, fp32 out
    {
        Segs s = {{inHi[3], inHi[3]}, {WoThi, WoTlo}};
        int nwgO = ((N + 63) / 64) * (O / 64);   // 157 * 2 = 314
        gemm_mfma<64, 64, false><<<nwgO, 256, 0, stream>>>(s, 2, bout, (float*)d_out, nullptr, N, O, O / 64, 0);
    }
}

// Round 8
// 320.083 us; speedup vs baseline: 2.6716x; 1.0528x over previous
//
#include <hip/hip_runtime.h>
#include <hip/hip_bf16.h>

#define KDIM 512

typedef _Float16 f16x8 __attribute__((ext_vector_type(8)));
typedef float f32x4 __attribute__((ext_vector_type(4)));
typedef unsigned short u16x8 __attribute__((ext_vector_type(8)));

static __device__ __forceinline__ unsigned short f2h(float v) {
    _Float16 h = (_Float16)v;
    return *reinterpret_cast<unsigned short*>(&h);
}
static __device__ __forceinline__ float h2f(unsigned short u) {
    _Float16 h = *reinterpret_cast<_Float16*>(&u);
    return (float)h;
}

// ---------------- CSR build ----------------

__global__ void deg_kernel(const int* __restrict__ dst, int* __restrict__ deg, int E) {
    int e = blockIdx.x * blockDim.x + threadIdx.x;
    if (e < E) atomicAdd(&deg[dst[e]], 1);
}

__global__ void scan_kernel(const int* __restrict__ deg, int* __restrict__ off, int n) {
    __shared__ int wsum[16];
    __shared__ int carry;
    int tid = threadIdx.x;
    int lane = tid & 63, wv = tid >> 6;
    if (tid == 0) carry = 0;
    __syncthreads();
    for (int start = 0; start < n; start += 1024) {
        int i = start + tid;
        int orig = (i < n) ? deg[i] : 0;
        int v = orig;
#pragma unroll
        for (int d = 1; d < 64; d <<= 1) {
            int t = __shfl_up(v, d, 64);
            if (lane >= d) v += t;
        }
        if (lane == 63) wsum[wv] = v;
        __syncthreads();
        int base = carry;
        if (wv == 0 && lane < 16) {
            int s = wsum[lane];
#pragma unroll
            for (int d = 1; d < 16; d <<= 1) {
                int t = __shfl_up(s, d, 64);
                if (lane >= d) s += t;
            }
            wsum[lane] = s;
            if (lane == 15) carry = base + s;
        }
        __syncthreads();
        int wpre = (wv == 0) ? 0 : wsum[wv - 1];
        if (i < n) off[i] = base + wpre + v - orig;   // exclusive
        __syncthreads();
    }
    if (tid == 0) off[n] = carry;
}

__global__ void fill_csr(const int* __restrict__ src, const int* __restrict__ dst,
                         const int* __restrict__ off, int* __restrict__ cursor,
                         int* __restrict__ csr_src, int E) {
    int e = blockIdx.x * blockDim.x + threadIdx.x;
    if (e < E) {
        int d = dst[e];
        int p = atomicAdd(&cursor[d], 1);
        csr_src[off[d] + p] = src[e];
    }
}

// ---------------- conversions ----------------

// x fp32 -> fp16 plane
__global__ void conv_x_kernel(const float* __restrict__ x,
                              unsigned short* __restrict__ hx, int total4) {
    int i = blockIdx.x * blockDim.x + threadIdx.x;
    if (i >= total4) return;
    float4 v = *(const float4*)(x + (size_t)i * 4);
    ushort4 h;
    h.x = f2h(v.x);
    h.y = f2h(v.y);
    h.z = f2h(v.z);
    h.w = f2h(v.w);
    *(ushort4*)(hx + (size_t)i * 4) = h;
}

// batched: 6 hidden-layer weight halves, W [512][512] fp32 -> W^T fp16 [512][512]
struct WBatch {
    const float* w[6];
    unsigned short* t[6];
};

__global__ void conv_w6(WBatch wb) {
    __shared__ float t[32][33];
    int li = blockIdx.z;
    const float* W = wb.w[li];
    unsigned short* T = wb.t[li];
    int tx = threadIdx.x & 31, ty = threadIdx.x >> 5;
    int k0 = blockIdx.x * 32, n0 = blockIdx.y * 32;
#pragma unroll
    for (int j = 0; j < 4; ++j) {
        int r = ty + j * 8;
        t[r][tx] = W[(size_t)(k0 + r) * 512 + n0 + tx];
    }
    __syncthreads();
#pragma unroll
    for (int j = 0; j < 4; ++j) {
        int rn = ty + j * 8;
        T[(size_t)(n0 + rn) * KDIM + k0 + tx] = f2h(t[tx][rn]);
    }
}

// W [512][Nw] fp32 -> W^T fp16 [Nw][512]
__global__ void conv_w_kernel(const float* __restrict__ W,
                              unsigned short* __restrict__ T, int Nw) {
    __shared__ float t[32][33];
    int tx = threadIdx.x & 31, ty = threadIdx.x >> 5;
    int k0 = blockIdx.x * 32, n0 = blockIdx.y * 32;
#pragma unroll
    for (int j = 0; j < 4; ++j) {
        int r = ty + j * 8;
        t[r][tx] = W[(size_t)(k0 + r) * Nw + n0 + tx];
    }
    __syncthreads();
#pragma unroll
    for (int j = 0; j < 4; ++j) {
        int rn = ty + j * 8;
        T[(size_t)(n0 + rn) * KDIM + k0 + tx] = f2h(t[tx][rn]);
    }
}

// ---------------- fp16 MFMA GEMM, K = 512 ----------------
// A [M][512] fp16, B (W^T) [Nw][512] fp16, C = A @ B^T.
// LDS XOR-swizzled via pre-swizzled global source; bijective XCD chunk map.

template<int BM, int BN, bool OUTBF>
__global__ __launch_bounds__(256) void gemm_mfma(
    const unsigned short* __restrict__ A, const unsigned short* __restrict__ B,
    const float* __restrict__ bias, float* __restrict__ outF,
    unsigned short* __restrict__ outB, int M, int ldo, int NBY, int relu) {
    constexpr int FM = BM / 32;
    constexpr int FN = BN / 32;
    __shared__ unsigned short As[BM * 64];
    __shared__ unsigned short Bs[BN * 64];

    int tid = threadIdx.x;
    int lane = tid & 63;
    int wid = tid >> 6;

    // bijective XCD chunk map (m204)
    int nwg = gridDim.x;
    int q = nwg >> 3, rres = nwg & 7;
    int xcd = blockIdx.x & 7;
    int tile = (xcd < rres ? xcd * (q + 1) : rres * (q + 1) + (xcd - rres) * q)
             + (blockIdx.x >> 3);
    int rowBase = (tile / NBY) * BM;
    int colBase = (tile % NBY) * BN;

    int wm = (wid >> 1) * (BM / 2);
    int wn = (wid & 1) * (BN / 2);

    f32x4 acc[FM][FN] = {};

    int srow = lane >> 3;                       // 0..7
    int scol = ((lane & 7) ^ srow) * 8;         // pre-swizzled source chunk

    for (int kt = 0; kt < 8; ++kt) {            // 8 x 64 = K 512
        int k0 = kt * 64;

#pragma unroll
        for (int s = 0; s < BM / 32; ++s) {
            int r0 = wid * (BM / 4) + s * 8;
            int gr = rowBase + r0 + srow;
            if (gr >= M) gr = M - 1;
            const unsigned short* g = A + (size_t)gr * KDIM + k0 + scol;
            __builtin_amdgcn_global_load_lds(
                (const __attribute__((address_space(1))) unsigned int*)g,
                (__attribute__((address_space(3))) unsigned int*)&As[r0 * 64],
                16, 0, 0);
        }
#pragma unroll
        for (int s = 0; s < BN / 32; ++s) {
            int r0 = wid * (BN / 4) + s * 8;
            const unsigned short* g = B + (size_t)(colBase + r0 + srow) * KDIM + k0 + scol;
            __builtin_amdgcn_global_load_lds(
                (const __attribute__((address_space(1))) unsigned int*)g,
                (__attribute__((address_space(3))) unsigned int*)&Bs[r0 * 64],
                16, 0, 0);
        }
        __syncthreads();

#pragma unroll
        for (int kk = 0; kk < 2; ++kk) {
            f16x8 aF[FM], bF[FN];
#pragma unroll
            for (int m = 0; m < FM; ++m) {
                int rr = wm + m * 16 + (lane & 15);
                int slot = ((kk << 2) + (lane >> 4)) ^ (lane & 7);
                aF[m] = *(const f16x8*)&As[rr * 64 + slot * 8];
            }
#pragma unroll
            for (int n = 0; n < FN; ++n) {
                int rn = wn + n * 16 + (lane & 15);
                int slot = ((kk << 2) + (lane >> 4)) ^ (lane & 7);
                bF[n] = *(const f16x8*)&Bs[rn * 64 + slot * 8];
            }
#pragma unroll
            for (int m = 0; m < FM; ++m)
#pragma unroll
                for (int n = 0; n < FN; ++n)
                    acc[m][n] = __builtin_amdgcn_mfma_f32_16x16x32_f16(aF[m], bF[n], acc[m][n], 0, 0, 0);
        }
        __syncthreads();
    }

#pragma unroll
    for (int n = 0; n < FN; ++n) {
        int col = colBase + wn + n * 16 + (lane & 15);
        float bb = bias ? bias[col] : 0.0f;
#pragma unroll
        for (int m = 0; m < FM; ++m) {
            int row0 = rowBase + wm + m * 16 + (lane >> 4) * 4;
#pragma unroll
            for (int r = 0; r < 4; ++r) {
                int row = row0 + r;
                if (row < M) {
                    float v = acc[m][n][r] + bb;
                    if (relu) v = fmaxf(v, 0.f);
                    if (OUTBF) outB[(size_t)row * ldo + col] = f2h(v);
                    else       outF[(size_t)row * ldo + col] = v;
                }
            }
        }
    }
}

// ---------------- column-sliced gather, 8-edge-parallel fp16 lanes ----------------
// P is fp16 [N][1024]. Wave = one (node, slice). lane = (esub 0..7) x (coct 0..7);
// each lane loads u16x8 (16B) for its edge; 8 edges in flight; inner loop 2x unrolled.
// Reduce esub groups via shfl_xor 8/16/32. XCD pin: slice = blockIdx & 7.
// out = fp16(relu(mean_gather(P[:,:512]) + P[:,512:] + b)).

__global__ __launch_bounds__(256) void gather_slice(
    const unsigned short* __restrict__ P, const int* __restrict__ off,
    const int* __restrict__ csr_src, const float* __restrict__ bias,
    unsigned short* __restrict__ oh, int n) {
    int slice = blockIdx.x & 7;
    int chunk = blockIdx.x >> 3;
    int wv = threadIdx.x >> 6;
    int lane = threadIdx.x & 63;
    int node = chunk * 4 + wv;
    if (node >= n) return;

    int esub = lane >> 3;                  // 0..7 edge sub-lane
    int c8 = slice * 64 + (lane & 7) * 8;  // absolute col oct base

    int beg = off[node], end = off[node + 1];
    float a[8] = {0.f, 0.f, 0.f, 0.f, 0.f, 0.f, 0.f, 0.f};
    int it = beg + esub;
    for (; it + 8 < end; it += 16) {       // two independent chains
        int s0 = csr_src[it];
        int s1 = csr_src[it + 8];
        u16x8 v0 = *(const u16x8*)(P + (size_t)s0 * 1024 + c8);
        u16x8 v1 = *(const u16x8*)(P + (size_t)s1 * 1024 + c8);
#pragma unroll
        for (int j = 0; j < 8; ++j) a[j] += h2f(v0[j]) + h2f(v1[j]);
    }
    if (it < end) {
        int s0 = csr_src[it];
        u16x8 v0 = *(const u16x8*)(P + (size_t)s0 * 1024 + c8);
#pragma unroll
        for (int j = 0; j < 8; ++j) a[j] += h2f(v0[j]);
    }
#pragma unroll
    for (int j = 0; j < 8; ++j) {
        a[j] += __shfl_xor(a[j], 8);
        a[j] += __shfl_xor(a[j], 16);
        a[j] += __shfl_xor(a[j], 32);
    }

    if (esub == 0) {   // lanes 0..7 finalize + store 16B each
        float inv = 1.0f / fmaxf((float)(end - beg), 1.0f);
        u16x8 p2 = *(const u16x8*)(P + (size_t)node * 1024 + 512 + c8);
        const float4* pb = (const float4*)(bias + c8);
        float4 b0 = pb[0], b1 = pb[1];
        float bbv[8] = {b0.x, b0.y, b0.z, b0.w, b1.x, b1.y, b1.z, b1.w};
        u16x8 h8;
#pragma unroll
        for (int j = 0; j < 8; ++j) {
            float v = fmaxf(a[j] * inv + h2f(p2[j]) + bbv[j], 0.f);
            h8[j] = f2h(v);
        }
        *(u16x8*)(oh + (size_t)node * KDIM + c8) = h8;
    }
}

// ---------------- launch ----------------

extern "C" void kernel_launch(void* const* d_in, const int* in_sizes, int n_in,
                              void* d_out, int out_size, void* d_ws, size_t ws_size,
                              hipStream_t stream) {
    const float* x    = (const float*)d_in[0];
    const int*   ei   = (const int*)d_in[1];
    const float* wl0  = (const float*)d_in[2];
    const float* bl0  = (const float*)d_in[3];
    const float* wr0  = (const float*)d_in[4];
    const float* wl1  = (const float*)d_in[5];
    const float* bl1  = (const float*)d_in[6];
    const float* wr1  = (const float*)d_in[7];
    const float* wl2  = (const float*)d_in[8];
    const float* bl2  = (const float*)d_in[9];
    const float* wr2  = (const float*)d_in[10];
    const float* wout = (const float*)d_in[11];
    const float* bout = (const float*)d_in[12];

    int N = in_sizes[0] / KDIM;     // 10000 nodes
    int E = in_sizes[1] / 2;        // 160000 edges
    int O = in_sizes[12];           // 128

    const int* src = ei;
    const int* dst = ei + E;

    char* ws = (char*)d_ws;
    auto align = [](size_t o) { return (o + 255) & ~(size_t)255; };
    size_t o = 0;
    int* deg     = (int*)(ws + o); o = align(o + (size_t)N * 4);
    int* cursor  = (int*)(ws + o); o = align(o + (size_t)N * 4);
    int* off     = (int*)(ws + o); o = align(o + (size_t)(N + 1) * 4);
    int* csr_src = (int*)(ws + o); o = align(o + (size_t)E * 4);

    size_t planeB = (size_t)N * KDIM * 2;
    unsigned short* x_h = (unsigned short*)(ws + o); o = align(o + planeB);
    unsigned short* a_h = (unsigned short*)(ws + o); o = align(o + planeB);
    unsigned short* P = (unsigned short*)(ws + o); o = align(o + (size_t)N * 1024 * 2);

    size_t whB = (size_t)1024 * KDIM * 2;
    unsigned short* WT[3];
    for (int i = 0; i < 3; ++i) { WT[i] = (unsigned short*)(ws + o); o = align(o + whB); }
    unsigned short* WoT = (unsigned short*)(ws + o); o = align(o + (size_t)O * KDIM * 2);

    hipMemsetAsync(deg, 0, (size_t)N * 4, stream);
    hipMemsetAsync(cursor, 0, (size_t)N * 4, stream);

    deg_kernel<<<(E + 255) / 256, 256, 0, stream>>>(dst, deg, E);
    scan_kernel<<<1, 1024, 0, stream>>>(deg, off, N);
    fill_csr<<<(E + 255) / 256, 256, 0, stream>>>(src, dst, off, cursor, csr_src, E);

    conv_x_kernel<<<(N * KDIM / 4 + 255) / 256, 256, 0, stream>>>(x, x_h, N * KDIM / 4);

    const float* wl[3] = {wl0, wl1, wl2};
    const float* wr[3] = {wr0, wr1, wr2};
    {
        WBatch wb;
        for (int i = 0; i < 3; ++i) {
            wb.w[i * 2 + 0] = wl[i];
            wb.t[i * 2 + 0] = WT[i];
            wb.w[i * 2 + 1] = wr[i];
            wb.t[i * 2 + 1] = WT[i] + (size_t)512 * KDIM;
        }
        dim3 wgrid(16, 16, 6);
        conv_w6<<<wgrid, 256, 0, stream>>>(wb);
    }
    dim3 wogrid(16, O / 32);
    conv_w_kernel<<<wogrid, 256, 0, stream>>>(wout, WoT, O);

    int nwgH = ((N + 63) / 64) * 8;            // 64x128 tiles: 157 * 8 = 1256
    int gatherBlocks = ((N + 3) / 4) * 8;      // 2500 chunks * 8 slices = 20000
    const float* bl[3] = {bl0, bl1, bl2};

    unsigned short* inH[4] = {x_h, a_h, x_h, a_h};

    for (int i = 0; i < 3; ++i) {
        // P = A @ [Wl|Wr]^T  (K = 512, fp16), fp16 out
        gemm_mfma<64, 128, true><<<nwgH, 256, 0, stream>>>(
            inH[i], WT[i], nullptr, nullptr, P, N, 1024, 8, 0);
        gather_slice<<<gatherBlocks, 256, 0, stream>>>(P, off, csr_src, bl[i], inH[i + 1], N);
    }

    // output projection: [N,512] @ [512,128] + bout, fp32 out
    {
        int nwgO = ((N + 63) / 64) * (O / 64);   // 157 * 2 = 314
        gemm_mfma<64, 64, false><<<nwgO, 256, 0, stream>>>(
            inH[3], WoT, bout, (float*)d_out, nullptr, N, O, O / 64, 0);
    }
}